// Round 3
// baseline (3833.846 us; speedup 1.0000x reference)
//
#include <hip/hip_runtime.h>
#include <hip/hip_bf16.h>

// ============================================================================
// PseudoLabelGenerator: round 9 — kernel fusion / latency hiding.
//   Stream is serial, but lstm (721us) leaves HBM ~idle (0.06%), L2/L3 idle,
//   half the wave slots free. Restructure 11 launches -> 6:
//     L1: probs U pack U hist          (independent)
//     L2: conf U mono-scan (1 block)   (scan chain collapsed, hidden)
//     L3: scatter
//     L4: lstm U gather_main, 1:1 blockIdx interleave (gather has NO dep on
//         lstm; its scattered-read latency hides in lstm's idle mem system)
//     L5: combine (tiny; the only consumer of lstm's wtc)
//   gather widened to 16 lanes/node (4 heads x 4 parities). lstm: setprio(1)
//   around MFMA clusters (real wave role diversity now), int4 h2-buf init,
//   __launch_bounds__(512,4) pins VGPR=128 so merge can't drop occupancy.
// ============================================================================

#define HIDN 256
#define NC 10
#define TSTEPS 12
#define NHEADS 4
#define LH 128

typedef __attribute__((ext_vector_type(8))) short short8;
typedef __attribute__((ext_vector_type(4))) float floatx4;

__device__ __forceinline__ unsigned short f2bf(float x) {
  unsigned u = __float_as_uint(x);
  u = u + 0x7FFFu + ((u >> 16) & 1u);   // round-to-nearest-even
  return (unsigned short)(u >> 16);
}
__device__ __forceinline__ unsigned char f2fp8(float x) {
  return (unsigned char)(__builtin_amdgcn_cvt_pk_fp8_f32(x, 0.f, 0, false) & 0xff);
}
__device__ __forceinline__ float fexp2(float x) { return __builtin_amdgcn_exp2f(x); }
__device__ __forceinline__ float frcpf(float x) { return __builtin_amdgcn_rcpf(x); }
#define LOG2E 1.44269504f
__device__ __forceinline__ float sigf(float x) {
  return frcpf(1.0f + fexp2(-LOG2E * x));
}
__device__ __forceinline__ float sig2(float x) {
  return frcpf(1.f + fexp2(-LOG2E * x));
}
__device__ __forceinline__ float tanh2(float x) {
  return 1.f - 2.f * frcpf(1.f + fexp2((2.f * LOG2E) * x));
}
__device__ __forceinline__ floatx4 mfma16(short8 a, short8 b, floatx4 c) {
  return __builtin_amdgcn_mfma_f32_16x16x32_bf16(a, b, c, 0, 0, 0);
}
__device__ __forceinline__ floatx4 mfma8(long a, long b, floatx4 c) {
  return __builtin_amdgcn_mfma_f32_16x16x32_fp8_fp8(a, b, c, 0, 0, 0);
}

// ---------------------------------------------------------------------------
// bodies for L1: probs / pack / hist
// ---------------------------------------------------------------------------
__device__ __forceinline__ void probs_body(
    int bb, float* sgW, float* sgas, float* sgad,
    const float* __restrict__ pred, const float* __restrict__ gW,
    const float* __restrict__ gas, const float* __restrict__ gad,
    float* __restrict__ out, float* __restrict__ wp12,
    float* __restrict__ was, float* __restrict__ wad,
    int* __restrict__ wlab, float* __restrict__ wmp, int N) {
  int tid = threadIdx.x;
  for (int i = tid; i < 400; i += 256) sgW[i] = gW[i];
  if (tid < 40) { sgas[tid] = gas[tid]; sgad[tid] = gad[tid]; }
  __syncthreads();
  int node = bb * 256 + tid;
  if (node >= N) return;
  const float* pr = pred + (size_t)node * NC;
  float p[NC];
#pragma unroll
  for (int c = 0; c < NC; c++) p[c] = pr[c];
  float pm = p[0]; int arg = 0;
#pragma unroll
  for (int c = 1; c < NC; c++) if (p[c] > pm) { pm = p[c]; arg = c; }
  float s = 0.f, prb[NC];
#pragma unroll
  for (int c = 0; c < NC; c++) { prb[c] = __expf(p[c] - pm); s += prb[c]; }
  float inv = 1.f / s;
  float ent = 0.f;
#pragma unroll
  for (int c = 0; c < NC; c++) {
    prb[c] *= inv;
    ent -= prb[c] * __logf(prb[c] + 1e-8f);
  }
  float4* wp = (float4*)(wp12 + (size_t)node * 12);
  wp[0] = make_float4(prb[0], prb[1], prb[2], prb[3]);
  wp[1] = make_float4(prb[4], prb[5], prb[6], prb[7]);
  wp[2] = make_float4(prb[8], prb[9], 0.f, 0.f);
  out[node] = (float)arg;
  out[(size_t)3 * N + node] = inv;
  out[(size_t)7 * N + node] = ent * (1.f / 2.302585093f);
  wlab[node] = arg;
  wmp[node] = inv;
  float xv[40];
#pragma unroll
  for (int hc = 0; hc < 40; hc++) {
    float t = 0.f;
#pragma unroll
    for (int k = 0; k < NC; k++) t += prb[k] * sgW[k * 40 + hc];
    xv[hc] = t;
  }
#pragma unroll
  for (int h = 0; h < NHEADS; h++) {
    float as = 0.f, ad = 0.f;
#pragma unroll
    for (int c = 0; c < NC; c++) { as += xv[h * 10 + c] * sgas[h * 10 + c]; ad += xv[h * 10 + c] * sgad[h * 10 + c]; }
    was[(size_t)node * 4 + h] = as;
    wad[(size_t)node * 4 + h] = ad;
  }
}

__device__ __forceinline__ void pack_body(
    int bb, const float* __restrict__ whh0, const float* __restrict__ wih0,
    const float* __restrict__ wih1, const float* __restrict__ whh1,
    const float* __restrict__ cw1,
    unsigned char* __restrict__ PB1, unsigned char* __restrict__ PB2,
    unsigned short* __restrict__ PBc) {
  int idx = bb * 256 + threadIdx.x;
  if (idx < 81920) {  // PB1: 5ks*8w*4g*64*8 bytes
    int j = idx & 7, lane = (idx >> 3) & 63, rest = idx >> 9;
    int g = rest & 3, w = (rest >> 2) & 7, ks = rest >> 5;
    int k = ks * 32 + ((lane >> 4) << 3) + j;
    int u = w * 16 + (lane & 15), row = g * 128 + u;
    float val = 0.f;
    if (k < 128) val = whh0[row * 128 + k];
    else if (k < 138) val = wih0[row * 10 + (k - 128)];
    PB1[idx] = f2fp8(val);
  }
  if (idx < 131072) {  // PB2: 8ks*8w*4g*64*8 bytes
    int j = idx & 7, lane = (idx >> 3) & 63, rest = idx >> 9;
    int g = rest & 3, w = (rest >> 2) & 7, ks = rest >> 5;
    int k = ks * 32 + ((lane >> 4) << 3) + j;
    int u = w * 16 + (lane & 15), row = g * 128 + u;
    float val = (k < 128) ? wih1[row * 128 + k] : whh1[row * 128 + (k - 128)];
    PB2[idx] = f2fp8(val);
  }
  if (idx < 32768) {  // PBc: 8*8*64*8 bf16
    int j = idx & 7, lane = (idx >> 3) & 63, t2 = idx >> 9;
    int ti = t2 & 7, ks = t2 >> 3;
    int n = ti * 16 + (lane & 15);
    int k = ks * 32 + ((lane >> 4) << 3) + j;
    PBc[idx] = f2bf(cw1[n * 256 + k]);
  }
}

__device__ __forceinline__ void hist_body(
    int bb, const int* __restrict__ ei, int* __restrict__ indeg,
    int* __restrict__ outdeg, int E, int N) {
  int idx = bb * 256 + threadIdx.x;
  if (idx >= E + N) return;
  int src, dst;
  if (idx < E) { src = ei[idx]; dst = ei[E + idx]; } else { src = dst = idx - E; }
  atomicAdd(&indeg[dst], 1);
  atomicAdd(&outdeg[src], 1);
}

// ---------------------------------------------------------------------------
// L1: probs U pack U hist
// ---------------------------------------------------------------------------
__global__ __launch_bounds__(256) void mega1_kernel(
    const float* __restrict__ pred, const float* __restrict__ gW,
    const float* __restrict__ gas, const float* __restrict__ gad,
    float* __restrict__ out, float* __restrict__ wp12,
    float* __restrict__ was, float* __restrict__ wad,
    int* __restrict__ wlab, float* __restrict__ wmp,
    const float* __restrict__ whh0, const float* __restrict__ wih0,
    const float* __restrict__ wih1, const float* __restrict__ whh1,
    const float* __restrict__ cw1,
    unsigned char* __restrict__ PB1, unsigned char* __restrict__ PB2,
    unsigned short* __restrict__ PBc,
    const int* __restrict__ ei, int* __restrict__ indeg, int* __restrict__ outdeg,
    int N, int E, int GP, int GK) {
  __shared__ float sgW[400], sgas[40], sgad[40];
  int b = blockIdx.x;
  if (b < GP) {
    probs_body(b, sgW, sgas, sgad, pred, gW, gas, gad, out, wp12, was, wad, wlab, wmp, N);
  } else if (b < GP + GK) {
    pack_body(b - GP, whh0, wih0, wih1, whh1, cw1, PB1, PB2, PBc);
  } else {
    hist_body(b - GP - GK, ei, indeg, outdeg, E, N);
  }
}

// ---------------------------------------------------------------------------
// bodies for L2: conf / mono-scan
// ---------------------------------------------------------------------------
__device__ __forceinline__ void conf_body(
    int bb, unsigned short* astage,
    const float* __restrict__ emb, const unsigned short* __restrict__ PBc,
    const float* __restrict__ cb1, const float* __restrict__ cw2,
    const float* __restrict__ cb2, float* __restrict__ wec, int N) {
  int tid = threadIdx.x;
  int base = bb * 128;
  for (int i = tid * 4; i < 128 * 256; i += 1024) {
    int row = i >> 8, col = i & 255;
    float4 v = make_float4(0.f, 0.f, 0.f, 0.f);
    if (base + row < N) v = *(const float4*)(emb + (size_t)(base + row) * 256 + col);
    unsigned short* d = &astage[row * 264 + col];
    d[0] = f2bf(v.x); d[1] = f2bf(v.y); d[2] = f2bf(v.z); d[3] = f2bf(v.w);
  }
  __syncthreads();
  int wave = tid >> 6, lane = tid & 63, quad = lane >> 4, ln = lane & 15;
  float b1f[8], w2f[8];
#pragma unroll
  for (int t = 0; t < 8; t++) { b1f[t] = cb1[t * 16 + ln]; w2f[t] = cw2[t * 16 + ln]; }
  floatx4 acc[2][8];
#pragma unroll
  for (int mi = 0; mi < 2; mi++)
#pragma unroll
    for (int t = 0; t < 8; t++) acc[mi][t] = (floatx4){b1f[t], b1f[t], b1f[t], b1f[t]};
#pragma unroll
  for (int ks = 0; ks < 8; ks++) {
    short8 a0 = *(const short8*)&astage[(wave * 32 + ln) * 264 + ks * 32 + quad * 8];
    short8 a1 = *(const short8*)&astage[(wave * 32 + 16 + ln) * 264 + ks * 32 + quad * 8];
    const unsigned short* bp = PBc + (((size_t)(ks * 8) * 64 + lane) << 3);
#pragma unroll
    for (int t = 0; t < 8; t++) {
      short8 b = *(const short8*)(bp + (size_t)t * 512);
      acc[0][t] = mfma16(a0, b, acc[0][t]);
      acc[1][t] = mfma16(a1, b, acc[1][t]);
    }
  }
  float part[2][4];
#pragma unroll
  for (int mi = 0; mi < 2; mi++)
#pragma unroll
    for (int r = 0; r < 4; r++) {
      float t = 0.f;
#pragma unroll
      for (int ti = 0; ti < 8; ti++) t += fmaxf(acc[mi][ti][r], 0.f) * w2f[ti];
      part[mi][r] = t;
    }
#pragma unroll
  for (int off = 8; off >= 1; off >>= 1)
#pragma unroll
    for (int mi = 0; mi < 2; mi++)
#pragma unroll
      for (int r = 0; r < 4; r++) part[mi][r] += __shfl_xor(part[mi][r], off);
  if (ln == 0) {
    float b2 = cb2[0];
#pragma unroll
    for (int mi = 0; mi < 2; mi++)
#pragma unroll
      for (int r = 0; r < 4; r++) {
        int node = base + wave * 32 + mi * 16 + quad * 4 + r;
        if (node < N) wec[node] = sigf(part[mi][r] + b2);
      }
  }
}

// single-block exclusive scan of indeg -> rowptr + cursor (256 threads)
__device__ __forceinline__ void scan_body(
    int* wsum, const int* __restrict__ indeg, int* __restrict__ rowptr,
    int* __restrict__ cursor, int N) {
  int t = threadIdx.x;
  int lane = t & 63, wv = t >> 6;
  int runbase = 0;
  for (int c0 = 0; c0 < N; c0 += 1024) {
    int i = c0 + t * 4;
    int v0 = 0, v1 = 0, v2 = 0, v3 = 0;
    if (i + 0 < N) v0 = indeg[i + 0];
    if (i + 1 < N) v1 = indeg[i + 1];
    if (i + 2 < N) v2 = indeg[i + 2];
    if (i + 3 < N) v3 = indeg[i + 3];
    int tsum = v0 + v1 + v2 + v3;
    int x = tsum;
#pragma unroll
    for (int d = 1; d < 64; d <<= 1) { int y = __shfl_up(x, d); if (lane >= d) x += y; }
    if (lane == 63) wsum[wv] = x;
    __syncthreads();
    int wo = 0;
    for (int w = 0; w < wv; w++) wo += wsum[w];
    int tot = wsum[0] + wsum[1] + wsum[2] + wsum[3];
    int excl = runbase + wo + x - tsum;
    if (i + 0 < N) { rowptr[i + 0] = excl; cursor[i + 0] = excl; }
    if (i + 1 < N) { rowptr[i + 1] = excl + v0; cursor[i + 1] = excl + v0; }
    if (i + 2 < N) { rowptr[i + 2] = excl + v0 + v1; cursor[i + 2] = excl + v0 + v1; }
    if (i + 3 < N) { rowptr[i + 3] = excl + v0 + v1 + v2; cursor[i + 3] = excl + v0 + v1 + v2; }
    runbase += tot;
    __syncthreads();
  }
  if (t == 0) rowptr[N] = runbase;
}

// ---------------------------------------------------------------------------
// L2: conf U mono-scan
// ---------------------------------------------------------------------------
__global__ __launch_bounds__(256) void mega2_kernel(
    const float* __restrict__ emb, const unsigned short* __restrict__ PBc,
    const float* __restrict__ cb1, const float* __restrict__ cw2,
    const float* __restrict__ cb2, float* __restrict__ wec,
    const int* __restrict__ indeg, int* __restrict__ rowptr,
    int* __restrict__ cursor, int N, int GC) {
  __shared__ __align__(16) unsigned short astage[128 * 264];
  int b = blockIdx.x;
  if (b < GC) {
    conf_body(b, astage, emb, PBc, cb1, cw2, cb2, wec, N);
  } else {
    scan_body((int*)astage, indeg, rowptr, cursor, N);
  }
}

// ---------------------------------------------------------------------------
// L3: scatter edges into CSR (1 int atomic per edge)
// ---------------------------------------------------------------------------
__global__ void scatter_kernel(const int* __restrict__ ei, int* __restrict__ cursor,
                               int* __restrict__ csr, int E, int N) {
  int idx = blockIdx.x * 256 + threadIdx.x;
  if (idx >= E + N) return;
  int src, dst;
  if (idx < E) { src = ei[idx]; dst = ei[E + idx]; } else { src = dst = idx - E; }
  int pos = atomicAdd(&cursor[dst], 1);
  csr[pos] = src;
}

// ---------------------------------------------------------------------------
// lstm body (32 nodes, 512 threads). setprio(1) around MFMA clusters.
// ---------------------------------------------------------------------------
#define HB2 4352  // 32*136

__device__ __forceinline__ void lstm_body(
    int bL, unsigned char* smem,
    const float* __restrict__ pred, const unsigned char* __restrict__ PB1,
    const unsigned char* __restrict__ PB2,
    const float* __restrict__ bih0, const float* __restrict__ bhh0,
    const float* __restrict__ bih1, const float* __restrict__ bhh1,
    float* __restrict__ wtc, int N) {
  unsigned char* hb = smem;                       // 4*HB2
  unsigned char* xbuf = smem + 4 * HB2;           // 1280
  float* varsum = (float*)(smem + 4 * HB2 + 1280);  // 32 floats
  int tid = threadIdx.x;
  int base = bL * 32;
  for (int i = tid * 4; i < HB2; i += 2048) *(int*)&hb[3 * HB2 + i] = 0;  // h2[-1]=0
  for (int i = tid; i < 32 * 40; i += 512) {
    int nd = i / 40, o = i - nd * 40;
    float v = 0.f;
    if (o < 10 && base + nd < N) v = pred[(size_t)(base + nd) * NC + o];
    xbuf[i] = f2fp8(v);
  }
  if (tid < 32) varsum[tid] = 0.f;
  int wave = tid >> 6, lane = tid & 63, quad = lane >> 4, ln = lane & 15;
  float b0f[4], b1f[4];
#pragma unroll
  for (int g = 0; g < 4; g++) {
    int row = g * 128 + wave * 16 + ln;
    b0f[g] = bih0[row] + bhh0[row];
    b1f[g] = bih1[row] + bhh1[row];
  }
  long w1r[5][4], w2r[8][4];
#pragma unroll
  for (int ks = 0; ks < 5; ks++)
#pragma unroll
    for (int g = 0; g < 4; g++)
      w1r[ks][g] = *(const long*)(PB1 + (size_t)(((ks * 8 + wave) * 4 + g) * 64 + lane) * 8);
#pragma unroll
  for (int ks = 0; ks < 8; ks++)
#pragma unroll
    for (int g = 0; g < 4; g++)
      w2r[ks][g] = *(const long*)(PB2 + (size_t)(((ks * 8 + wave) * 4 + g) * 64 + lane) * 8);
  float c1[8], c2[8], s1[8], s2[8];
#pragma unroll
  for (int i = 0; i < 8; i++) { c1[i] = 0.f; c2[i] = 0.f; s1[i] = 0.f; s2[i] = 0.f; }
  const int hq = quad * 8;
  const int ucol = wave * 16 + ln;
  int arow[2], wrow[2];
#pragma unroll
  for (int mt = 0; mt < 2; mt++) {
    arow[mt] = (mt * 16 + ln) * 136 + hq;
    wrow[mt] = (mt * 16 + quad * 4) * 136 + ucol;
  }
  __syncthreads();  // xbuf ready
  long xa[2];
  xa[0] = *(const long*)&xbuf[ln * 40 + hq];
  xa[1] = *(const long*)&xbuf[(16 + ln) * 40 + hq];

  // ----- prime: phase1(t=0), h1 state = 0 -----
  {
    floatx4 acc[2][4];
#pragma unroll
    for (int mt = 0; mt < 2; mt++)
#pragma unroll
      for (int g = 0; g < 4; g++) acc[mt][g] = (floatx4){b0f[g], b0f[g], b0f[g], b0f[g]};
#pragma unroll
    for (int g = 0; g < 4; g++)
#pragma unroll
      for (int mt = 0; mt < 2; mt++) acc[mt][g] = mfma8(xa[mt], w1r[4][g], acc[mt][g]);
#pragma unroll
    for (int mt = 0; mt < 2; mt++)
#pragma unroll
      for (int r = 0; r < 4; r++) {
        int ci = mt * 4 + r;
        float ig = sig2(acc[mt][0][r]);
        float gg = tanh2(acc[mt][2][r]);
        float og = sig2(acc[mt][3][r]);
        float c = ig * gg;
        c1[ci] = c;
        hb[0 + wrow[mt] + r * 136] = f2fp8(og * tanh2(c));
      }
  }

#define LSTM_SEG(O1R, O1W, O2R, O2W, lastseg)                                    \
  {                                                                              \
    __syncthreads();                                                             \
    floatx4 acc[2][4];                                                           \
    _Pragma("unroll") for (int mt = 0; mt < 2; mt++)                             \
        _Pragma("unroll") for (int g = 0; g < 4; g++)                            \
            acc[mt][g] = (floatx4){b1f[g], b1f[g], b1f[g], b1f[g]};              \
    __builtin_amdgcn_s_setprio(1);                                               \
    _Pragma("unroll") for (int ks = 0; ks < 8; ks++) {                           \
      long a_[2];                                                                \
      if (ks < 4) {                                                              \
        _Pragma("unroll") for (int mt = 0; mt < 2; mt++)                         \
            a_[mt] = *(const long*)&hb[(O1R) + arow[mt] + ks * 32];              \
      } else {                                                                   \
        _Pragma("unroll") for (int mt = 0; mt < 2; mt++)                         \
            a_[mt] = *(const long*)&hb[(O2R) + arow[mt] + (ks - 4) * 32];        \
      }                                                                          \
      _Pragma("unroll") for (int g = 0; g < 4; g++)                              \
          _Pragma("unroll") for (int mt = 0; mt < 2; mt++)                       \
              acc[mt][g] = mfma8(a_[mt], w2r[ks][g], acc[mt][g]);                \
    }                                                                            \
    __builtin_amdgcn_s_setprio(0);                                               \
    _Pragma("unroll") for (int mt = 0; mt < 2; mt++)                             \
        _Pragma("unroll") for (int r = 0; r < 4; r++) {                          \
      int ci = mt * 4 + r;                                                       \
      float ig = sig2(acc[mt][0][r]);                                            \
      float fg = sig2(acc[mt][1][r]);                                            \
      float gg = tanh2(acc[mt][2][r]);                                           \
      float og = sig2(acc[mt][3][r]);                                            \
      float c = fg * c2[ci] + ig * gg;                                           \
      c2[ci] = c;                                                                \
      float h = og * tanh2(c);                                                   \
      s1[ci] += h;                                                               \
      s2[ci] += h * h;                                                           \
      hb[(O2W) + wrow[mt] + r * 136] = f2fp8(h);                                 \
    }                                                                            \
    if (!(lastseg)) {                                                            \
      _Pragma("unroll") for (int mt = 0; mt < 2; mt++)                           \
          _Pragma("unroll") for (int g = 0; g < 4; g++)                          \
              acc[mt][g] = (floatx4){b0f[g], b0f[g], b0f[g], b0f[g]};            \
      __builtin_amdgcn_s_setprio(1);                                             \
      _Pragma("unroll") for (int ks = 0; ks < 5; ks++) {                         \
        long a_[2];                                                              \
        if (ks < 4) {                                                            \
          _Pragma("unroll") for (int mt = 0; mt < 2; mt++)                       \
              a_[mt] = *(const long*)&hb[(O1R) + arow[mt] + ks * 32];            \
        } else {                                                                 \
          a_[0] = xa[0]; a_[1] = xa[1];                                          \
        }                                                                        \
        _Pragma("unroll") for (int g = 0; g < 4; g++)                            \
            _Pragma("unroll") for (int mt = 0; mt < 2; mt++)                     \
                acc[mt][g] = mfma8(a_[mt], w1r[ks][g], acc[mt][g]);              \
      }                                                                          \
      __builtin_amdgcn_s_setprio(0);                                             \
      _Pragma("unroll") for (int mt = 0; mt < 2; mt++)                           \
          _Pragma("unroll") for (int r = 0; r < 4; r++) {                        \
        int ci = mt * 4 + r;                                                     \
        float ig = sig2(acc[mt][0][r]);                                          \
        float fg = sig2(acc[mt][1][r]);                                          \
        float gg = tanh2(acc[mt][2][r]);                                         \
        float og = sig2(acc[mt][3][r]);                                          \
        float c = fg * c1[ci] + ig * gg;                                         \
        c1[ci] = c;                                                              \
        hb[(O1W) + wrow[mt] + r * 136] = f2fp8(og * tanh2(c));                   \
      }                                                                          \
    }                                                                            \
  }

  for (int tt = 0; tt < TSTEPS / 2; tt++) {
    LSTM_SEG(0, HB2, 3 * HB2, 2 * HB2, false);
    LSTM_SEG(HB2, 0, 2 * HB2, 3 * HB2, tt == TSTEPS / 2 - 1);
  }
#undef LSTM_SEG

#pragma unroll
  for (int mt = 0; mt < 2; mt++)
#pragma unroll
    for (int r = 0; r < 4; r++) {
      int ci = mt * 4 + r;
      float m = s1[ci] * (1.f / 12.f);
      float var = (s2[ci] - 12.f * m * m) * (1.f / 11.f);
      atomicAdd(&varsum[mt * 16 + quad * 4 + r], var);
    }
  __syncthreads();
  if (tid < 32 && base + tid < N)
    wtc[base + tid] = 1.f / (1.f + varsum[tid] * (1.f / 128.f));
}

// ---------------------------------------------------------------------------
// gather body: 16 lanes/node (head h = sub&3, parity par = sub>>2, 4-way).
// Writes wgc (graph confidence) + wag (neighborhood agreement ratio); the
// final combine kernel (the only wtc consumer) merges everything.
// ---------------------------------------------------------------------------
__device__ __forceinline__ void gather_body(
    int bg, unsigned char* smem,
    const int* __restrict__ rowptr, const int* __restrict__ csr,
    const float* __restrict__ was, const float* __restrict__ wad,
    const float* __restrict__ wp12, const int* __restrict__ wlab,
    const int* __restrict__ outdeg, const float* __restrict__ gW,
    const float* __restrict__ gb, float* __restrict__ wgc,
    float* __restrict__ wag, int N) {
  float* sgW = (float*)smem;
  int tid = threadIdx.x;
  for (int i = tid; i < 400; i += 512) sgW[i] = gW[i];
  __syncthreads();
  int vgid = bg * 512 + tid;
  int node = vgid >> 4, sub = vgid & 15, h = sub & 3, par = sub >> 2;
  if (node >= N) return;
  int beg = rowptr[node], end = rowptr[node + 1];
  float ad = wad[(size_t)node * 4 + h];
  int mylab = wlab[node];
  float ssum = 0.f, cnt = 0.f;
  float z[10];
#pragma unroll
  for (int c = 0; c < 10; c++) z[c] = 0.f;
  for (int e = beg + par; e < end; e += 4) {
    int s = csr[e];
    float v = was[(size_t)s * 4 + h] + ad;
    float lr = v >= 0.f ? v : 0.2f * v;
    float ex = fexp2(LOG2E * lr);  // bounded logits: no max-sub needed
    ssum += ex;
    const float4* pp = (const float4*)(wp12 + (size_t)s * 12);
    float4 p0 = pp[0], p1 = pp[1], p2 = pp[2];
    z[0] += ex * p0.x; z[1] += ex * p0.y; z[2] += ex * p0.z; z[3] += ex * p0.w;
    z[4] += ex * p1.x; z[5] += ex * p1.y; z[6] += ex * p1.z; z[7] += ex * p1.w;
    z[8] += ex * p2.x; z[9] += ex * p2.y;
    cnt += (wlab[s] == mylab) ? 1.f : 0.f;
  }
  // combine 4 edge parities (lane bits 2,3)
  ssum += __shfl_xor(ssum, 4); ssum += __shfl_xor(ssum, 8);
  cnt  += __shfl_xor(cnt, 4);  cnt  += __shfl_xor(cnt, 8);
#pragma unroll
  for (int c = 0; c < 10; c++) { z[c] += __shfl_xor(z[c], 4); z[c] += __shfl_xor(z[c], 8); }
  float inv = 1.f / (ssum + 1e-16f);
  float gpart[10];
#pragma unroll
  for (int c = 0; c < 10; c++) {
    float t = 0.f;
#pragma unroll
    for (int k = 0; k < 10; k++) t += z[k] * sgW[k * 40 + h * 10 + c];
    gpart[c] = t * inv;
  }
  // head mean reduce (lane bits 0,1)
#pragma unroll
  for (int c = 0; c < 10; c++) {
    gpart[c] += __shfl_xor(gpart[c], 1);
    gpart[c] += __shfl_xor(gpart[c], 2);
  }
  if (sub == 0) {
    float num = 0.f, np2 = 0.f, ng2 = 0.f;
    const float* pn = wp12 + (size_t)node * 12;
#pragma unroll
    for (int c = 0; c < 10; c++) {
      float g = gpart[c] * 0.25f + gb[c];
      float p = pn[c];
      num += p * g;
      np2 += p * p;
      ng2 += g * g;
    }
    float den = fmaxf(sqrtf(np2) * sqrtf(ng2), 1e-8f);
    wgc[node] = (num / den + 1.f) * 0.5f;
    float dgv = (float)outdeg[node];
    wag[node] = cnt / (dgv + 1e-8f);
  }
}

// ---------------------------------------------------------------------------
// L4: lstm U gather_main, 1:1 interleave (gather has no dependency on lstm)
// ---------------------------------------------------------------------------
__global__ __launch_bounds__(512, 4) void mega4_kernel(
    const float* __restrict__ pred, const unsigned char* __restrict__ PB1,
    const unsigned char* __restrict__ PB2,
    const float* __restrict__ bih0, const float* __restrict__ bhh0,
    const float* __restrict__ bih1, const float* __restrict__ bhh1,
    float* __restrict__ wtc,
    const int* __restrict__ rowptr, const int* __restrict__ csr,
    const float* __restrict__ was, const float* __restrict__ wad,
    const float* __restrict__ wp12, const int* __restrict__ wlab,
    const int* __restrict__ outdeg, const float* __restrict__ gW,
    const float* __restrict__ gb, float* __restrict__ wgc, float* __restrict__ wag,
    int N, int GL, int GG) {
  __shared__ __align__(16) unsigned char smem[4 * HB2 + 1280 + 128];
  int b = blockIdx.x;
  int mn = GL < GG ? GL : GG, m2 = 2 * mn;
  int isL, idx;
  if (b < m2) { isL = !(b & 1); idx = b >> 1; }
  else { isL = (GL > GG) ? 1 : 0; idx = mn + (b - m2); }
  if (isL) {
    lstm_body(idx, smem, pred, PB1, PB2, bih0, bhh0, bih1, bhh1, wtc, N);
  } else {
    gather_body(idx, smem, rowptr, csr, was, wad, wp12, wlab, outdeg, gW, gb,
                wgc, wag, N);
  }
}

// ---------------------------------------------------------------------------
// L5: combine (only consumer of lstm's wtc)
// ---------------------------------------------------------------------------
__global__ void combine_kernel(const float* __restrict__ wmp,
                               const float* __restrict__ wec,
                               const float* __restrict__ wtc,
                               const float* __restrict__ wgc,
                               const float* __restrict__ wag,
                               float* __restrict__ out, int N) {
  int node = blockIdx.x * 256 + threadIdx.x;
  if (node >= N) return;
  float mp = wmp[node], ec = wec[node], tc = wtc[node], gc = wgc[node];
  float comb = 0.4f * mp + 0.2f * ec + 0.2f * tc + 0.2f * gc;
  bool mask = (comb > 0.85f) && (wag[node] >= 0.6f);
  out[(size_t)1 * N + node] = comb;
  out[(size_t)2 * N + node] = mask ? 1.f : 0.f;
  out[(size_t)4 * N + node] = ec;
  out[(size_t)5 * N + node] = tc;
  out[(size_t)6 * N + node] = gc;
}

// ---------------------------------------------------------------------------
extern "C" void kernel_launch(void* const* d_in, const int* in_sizes, int n_in,
                              void* d_out, int out_size, void* d_ws, size_t ws_size,
                              hipStream_t stream) {
  const float* emb  = (const float*)d_in[0];
  const float* pred = (const float*)d_in[1];
  const int*   ei   = (const int*)d_in[3];
  const float* cw1  = (const float*)d_in[4];
  const float* cb1  = (const float*)d_in[5];
  const float* cw2  = (const float*)d_in[6];
  const float* cb2  = (const float*)d_in[7];
  const float* wih0 = (const float*)d_in[8];
  const float* whh0 = (const float*)d_in[9];
  const float* bih0 = (const float*)d_in[10];
  const float* bhh0 = (const float*)d_in[11];
  const float* wih1 = (const float*)d_in[12];
  const float* whh1 = (const float*)d_in[13];
  const float* bih1 = (const float*)d_in[14];
  const float* bhh1 = (const float*)d_in[15];
  const float* gW   = (const float*)d_in[16];
  const float* gas  = (const float*)d_in[17];
  const float* gad  = (const float*)d_in[18];
  const float* gb   = (const float*)d_in[19];

  const int N = in_sizes[0] / HIDN;
  const int E = in_sizes[3] / 2;
  float* out = (float*)d_out;
  float* ws = (float*)d_ws;
  const size_t sN = (size_t)N;

  float* wp12   = ws;                         // 12N
  float* was    = ws + 12 * sN;               // 4N
  float* wad    = ws + 16 * sN;               // 4N
  int*   wlab   = (int*)(ws + 20 * sN);       // N
  float* wmp    = ws + 21 * sN;               // N
  float* wec    = ws + 22 * sN;               // N
  float* wtc    = ws + 23 * sN;               // N
  float* wgc    = ws + 24 * sN;               // N
  float* wag    = ws + 25 * sN;               // N
  int* indeg    = (int*)(ws + 26 * sN);       // N   <- memset region start
  int* outdeg   = (int*)(ws + 27 * sN);       // N   <- memset region end
  int* rowptr   = (int*)(ws + 28 * sN);       // N+1 (+pad)
  int* cursor   = (int*)(ws + 29 * sN) + 64;  // N
  int* csr      = (int*)(ws + 30 * sN) + 128; // E+N
  float* pbase  = ws + 31 * sN + 128 + E;
  unsigned char* PB1 = (unsigned char*)pbase;                  // 81920 B
  unsigned char* PB2 = (unsigned char*)(pbase + 20480);        // 131072 B
  unsigned short* PBc = (unsigned short*)(pbase + 53248);      // 32768 ushort

  hipMemsetAsync(indeg, 0, 2 * sN * sizeof(int), stream);

  // L1: probs U pack U hist
  int GP = (N + 255) / 256, GK = 512, GH = (E + N + 255) / 256;
  mega1_kernel<<<GP + GK + GH, 256, 0, stream>>>(
      pred, gW, gas, gad, out, wp12, was, wad, wlab, wmp,
      whh0, wih0, wih1, whh1, cw1, PB1, PB2, PBc,
      ei, indeg, outdeg, N, E, GP, GK);

  // L2: conf U mono-scan
  int GC = (N + 127) / 128;
  mega2_kernel<<<GC + 1, 256, 0, stream>>>(
      emb, PBc, cb1, cw2, cb2, wec, indeg, rowptr, cursor, N, GC);

  // L3: scatter
  int ne = E + N;
  scatter_kernel<<<(ne + 255) / 256, 256, 0, stream>>>(ei, cursor, csr, E, N);

  // L4: lstm U gather (1:1 interleave)
  int GL = (N + 31) / 32;
  int GG = (16 * N + 511) / 512;
  mega4_kernel<<<GL + GG, 512, 0, stream>>>(
      pred, PB1, PB2, bih0, bhh0, bih1, bhh1, wtc,
      rowptr, csr, was, wad, wp12, wlab, outdeg, gW, gb, wgc, wag,
      N, GL, GG);

  // L5: combine
  combine_kernel<<<(N + 255) / 256, 256, 0, stream>>>(wmp, wec, wtc, wgc, wag, out, N);
}

// Round 4
// 2139.990 us; speedup vs baseline: 1.7915x; 1.7915x over previous
//
#include <hip/hip_runtime.h>
#include <hip/hip_bf16.h>

// ============================================================================
// PseudoLabelGenerator: round 10 — fix round-9's spill catastrophe.
//   Round 9's ONLY defect: mega4 __launch_bounds__(512,4) forced the ~190-reg
//   lstm working set into 64 VGPRs -> w1r/w2r spilled to scratch -> 7 GB HBM
//   traffic, 3.1ms. Restore the proven (512,2) bound (lstm compiled 124-128
//   VGPR spill-free under it for 3 rounds). Fusion structure retained:
//     L1: probs U pack U hist
//     L2: conf U mono-scan
//     L3: scatter
//     L4: lstm U gather (1:1 interleave; gather has no dep on lstm)
//     L5: combine
// ============================================================================

#define HIDN 256
#define NC 10
#define TSTEPS 12
#define NHEADS 4
#define LH 128

typedef __attribute__((ext_vector_type(8))) short short8;
typedef __attribute__((ext_vector_type(4))) float floatx4;

__device__ __forceinline__ unsigned short f2bf(float x) {
  unsigned u = __float_as_uint(x);
  u = u + 0x7FFFu + ((u >> 16) & 1u);   // round-to-nearest-even
  return (unsigned short)(u >> 16);
}
__device__ __forceinline__ unsigned char f2fp8(float x) {
  return (unsigned char)(__builtin_amdgcn_cvt_pk_fp8_f32(x, 0.f, 0, false) & 0xff);
}
__device__ __forceinline__ float fexp2(float x) { return __builtin_amdgcn_exp2f(x); }
__device__ __forceinline__ float frcpf(float x) { return __builtin_amdgcn_rcpf(x); }
#define LOG2E 1.44269504f
__device__ __forceinline__ float sigf(float x) {
  return frcpf(1.0f + fexp2(-LOG2E * x));
}
__device__ __forceinline__ float sig2(float x) {
  return frcpf(1.f + fexp2(-LOG2E * x));
}
__device__ __forceinline__ float tanh2(float x) {
  return 1.f - 2.f * frcpf(1.f + fexp2((2.f * LOG2E) * x));
}
__device__ __forceinline__ floatx4 mfma16(short8 a, short8 b, floatx4 c) {
  return __builtin_amdgcn_mfma_f32_16x16x32_bf16(a, b, c, 0, 0, 0);
}
__device__ __forceinline__ floatx4 mfma8(long a, long b, floatx4 c) {
  return __builtin_amdgcn_mfma_f32_16x16x32_fp8_fp8(a, b, c, 0, 0, 0);
}

// ---------------------------------------------------------------------------
// bodies for L1: probs / pack / hist
// ---------------------------------------------------------------------------
__device__ __forceinline__ void probs_body(
    int bb, float* sgW, float* sgas, float* sgad,
    const float* __restrict__ pred, const float* __restrict__ gW,
    const float* __restrict__ gas, const float* __restrict__ gad,
    float* __restrict__ out, float* __restrict__ wp12,
    float* __restrict__ was, float* __restrict__ wad,
    int* __restrict__ wlab, float* __restrict__ wmp, int N) {
  int tid = threadIdx.x;
  for (int i = tid; i < 400; i += 256) sgW[i] = gW[i];
  if (tid < 40) { sgas[tid] = gas[tid]; sgad[tid] = gad[tid]; }
  __syncthreads();
  int node = bb * 256 + tid;
  if (node >= N) return;
  const float* pr = pred + (size_t)node * NC;
  float p[NC];
#pragma unroll
  for (int c = 0; c < NC; c++) p[c] = pr[c];
  float pm = p[0]; int arg = 0;
#pragma unroll
  for (int c = 1; c < NC; c++) if (p[c] > pm) { pm = p[c]; arg = c; }
  float s = 0.f, prb[NC];
#pragma unroll
  for (int c = 0; c < NC; c++) { prb[c] = __expf(p[c] - pm); s += prb[c]; }
  float inv = 1.f / s;
  float ent = 0.f;
#pragma unroll
  for (int c = 0; c < NC; c++) {
    prb[c] *= inv;
    ent -= prb[c] * __logf(prb[c] + 1e-8f);
  }
  float4* wp = (float4*)(wp12 + (size_t)node * 12);
  wp[0] = make_float4(prb[0], prb[1], prb[2], prb[3]);
  wp[1] = make_float4(prb[4], prb[5], prb[6], prb[7]);
  wp[2] = make_float4(prb[8], prb[9], 0.f, 0.f);
  out[node] = (float)arg;
  out[(size_t)3 * N + node] = inv;
  out[(size_t)7 * N + node] = ent * (1.f / 2.302585093f);
  wlab[node] = arg;
  wmp[node] = inv;
  float xv[40];
#pragma unroll
  for (int hc = 0; hc < 40; hc++) {
    float t = 0.f;
#pragma unroll
    for (int k = 0; k < NC; k++) t += prb[k] * sgW[k * 40 + hc];
    xv[hc] = t;
  }
#pragma unroll
  for (int h = 0; h < NHEADS; h++) {
    float as = 0.f, ad = 0.f;
#pragma unroll
    for (int c = 0; c < NC; c++) { as += xv[h * 10 + c] * sgas[h * 10 + c]; ad += xv[h * 10 + c] * sgad[h * 10 + c]; }
    was[(size_t)node * 4 + h] = as;
    wad[(size_t)node * 4 + h] = ad;
  }
}

__device__ __forceinline__ void pack_body(
    int bb, const float* __restrict__ whh0, const float* __restrict__ wih0,
    const float* __restrict__ wih1, const float* __restrict__ whh1,
    const float* __restrict__ cw1,
    unsigned char* __restrict__ PB1, unsigned char* __restrict__ PB2,
    unsigned short* __restrict__ PBc) {
  int idx = bb * 256 + threadIdx.x;
  if (idx < 81920) {  // PB1: 5ks*8w*4g*64*8 bytes
    int j = idx & 7, lane = (idx >> 3) & 63, rest = idx >> 9;
    int g = rest & 3, w = (rest >> 2) & 7, ks = rest >> 5;
    int k = ks * 32 + ((lane >> 4) << 3) + j;
    int u = w * 16 + (lane & 15), row = g * 128 + u;
    float val = 0.f;
    if (k < 128) val = whh0[row * 128 + k];
    else if (k < 138) val = wih0[row * 10 + (k - 128)];
    PB1[idx] = f2fp8(val);
  }
  if (idx < 131072) {  // PB2: 8ks*8w*4g*64*8 bytes
    int j = idx & 7, lane = (idx >> 3) & 63, rest = idx >> 9;
    int g = rest & 3, w = (rest >> 2) & 7, ks = rest >> 5;
    int k = ks * 32 + ((lane >> 4) << 3) + j;
    int u = w * 16 + (lane & 15), row = g * 128 + u;
    float val = (k < 128) ? wih1[row * 128 + k] : whh1[row * 128 + (k - 128)];
    PB2[idx] = f2fp8(val);
  }
  if (idx < 32768) {  // PBc: 8*8*64*8 bf16
    int j = idx & 7, lane = (idx >> 3) & 63, t2 = idx >> 9;
    int ti = t2 & 7, ks = t2 >> 3;
    int n = ti * 16 + (lane & 15);
    int k = ks * 32 + ((lane >> 4) << 3) + j;
    PBc[idx] = f2bf(cw1[n * 256 + k]);
  }
}

__device__ __forceinline__ void hist_body(
    int bb, const int* __restrict__ ei, int* __restrict__ indeg,
    int* __restrict__ outdeg, int E, int N) {
  int idx = bb * 256 + threadIdx.x;
  if (idx >= E + N) return;
  int src, dst;
  if (idx < E) { src = ei[idx]; dst = ei[E + idx]; } else { src = dst = idx - E; }
  atomicAdd(&indeg[dst], 1);
  atomicAdd(&outdeg[src], 1);
}

// ---------------------------------------------------------------------------
// L1: probs U pack U hist
// ---------------------------------------------------------------------------
__global__ __launch_bounds__(256) void mega1_kernel(
    const float* __restrict__ pred, const float* __restrict__ gW,
    const float* __restrict__ gas, const float* __restrict__ gad,
    float* __restrict__ out, float* __restrict__ wp12,
    float* __restrict__ was, float* __restrict__ wad,
    int* __restrict__ wlab, float* __restrict__ wmp,
    const float* __restrict__ whh0, const float* __restrict__ wih0,
    const float* __restrict__ wih1, const float* __restrict__ whh1,
    const float* __restrict__ cw1,
    unsigned char* __restrict__ PB1, unsigned char* __restrict__ PB2,
    unsigned short* __restrict__ PBc,
    const int* __restrict__ ei, int* __restrict__ indeg, int* __restrict__ outdeg,
    int N, int E, int GP, int GK) {
  __shared__ float sgW[400], sgas[40], sgad[40];
  int b = blockIdx.x;
  if (b < GP) {
    probs_body(b, sgW, sgas, sgad, pred, gW, gas, gad, out, wp12, was, wad, wlab, wmp, N);
  } else if (b < GP + GK) {
    pack_body(b - GP, whh0, wih0, wih1, whh1, cw1, PB1, PB2, PBc);
  } else {
    hist_body(b - GP - GK, ei, indeg, outdeg, E, N);
  }
}

// ---------------------------------------------------------------------------
// bodies for L2: conf / mono-scan
// ---------------------------------------------------------------------------
__device__ __forceinline__ void conf_body(
    int bb, unsigned short* astage,
    const float* __restrict__ emb, const unsigned short* __restrict__ PBc,
    const float* __restrict__ cb1, const float* __restrict__ cw2,
    const float* __restrict__ cb2, float* __restrict__ wec, int N) {
  int tid = threadIdx.x;
  int base = bb * 128;
  for (int i = tid * 4; i < 128 * 256; i += 1024) {
    int row = i >> 8, col = i & 255;
    float4 v = make_float4(0.f, 0.f, 0.f, 0.f);
    if (base + row < N) v = *(const float4*)(emb + (size_t)(base + row) * 256 + col);
    unsigned short* d = &astage[row * 264 + col];
    d[0] = f2bf(v.x); d[1] = f2bf(v.y); d[2] = f2bf(v.z); d[3] = f2bf(v.w);
  }
  __syncthreads();
  int wave = tid >> 6, lane = tid & 63, quad = lane >> 4, ln = lane & 15;
  float b1f[8], w2f[8];
#pragma unroll
  for (int t = 0; t < 8; t++) { b1f[t] = cb1[t * 16 + ln]; w2f[t] = cw2[t * 16 + ln]; }
  floatx4 acc[2][8];
#pragma unroll
  for (int mi = 0; mi < 2; mi++)
#pragma unroll
    for (int t = 0; t < 8; t++) acc[mi][t] = (floatx4){b1f[t], b1f[t], b1f[t], b1f[t]};
#pragma unroll
  for (int ks = 0; ks < 8; ks++) {
    short8 a0 = *(const short8*)&astage[(wave * 32 + ln) * 264 + ks * 32 + quad * 8];
    short8 a1 = *(const short8*)&astage[(wave * 32 + 16 + ln) * 264 + ks * 32 + quad * 8];
    const unsigned short* bp = PBc + (((size_t)(ks * 8) * 64 + lane) << 3);
#pragma unroll
    for (int t = 0; t < 8; t++) {
      short8 b = *(const short8*)(bp + (size_t)t * 512);
      acc[0][t] = mfma16(a0, b, acc[0][t]);
      acc[1][t] = mfma16(a1, b, acc[1][t]);
    }
  }
  float part[2][4];
#pragma unroll
  for (int mi = 0; mi < 2; mi++)
#pragma unroll
    for (int r = 0; r < 4; r++) {
      float t = 0.f;
#pragma unroll
      for (int ti = 0; ti < 8; ti++) t += fmaxf(acc[mi][ti][r], 0.f) * w2f[ti];
      part[mi][r] = t;
    }
#pragma unroll
  for (int off = 8; off >= 1; off >>= 1)
#pragma unroll
    for (int mi = 0; mi < 2; mi++)
#pragma unroll
      for (int r = 0; r < 4; r++) part[mi][r] += __shfl_xor(part[mi][r], off);
  if (ln == 0) {
    float b2 = cb2[0];
#pragma unroll
    for (int mi = 0; mi < 2; mi++)
#pragma unroll
      for (int r = 0; r < 4; r++) {
        int node = base + wave * 32 + mi * 16 + quad * 4 + r;
        if (node < N) wec[node] = sigf(part[mi][r] + b2);
      }
  }
}

// single-block exclusive scan of indeg -> rowptr + cursor (256 threads)
__device__ __forceinline__ void scan_body(
    int* wsum, const int* __restrict__ indeg, int* __restrict__ rowptr,
    int* __restrict__ cursor, int N) {
  int t = threadIdx.x;
  int lane = t & 63, wv = t >> 6;
  int runbase = 0;
  for (int c0 = 0; c0 < N; c0 += 1024) {
    int i = c0 + t * 4;
    int v0 = 0, v1 = 0, v2 = 0, v3 = 0;
    if (i + 0 < N) v0 = indeg[i + 0];
    if (i + 1 < N) v1 = indeg[i + 1];
    if (i + 2 < N) v2 = indeg[i + 2];
    if (i + 3 < N) v3 = indeg[i + 3];
    int tsum = v0 + v1 + v2 + v3;
    int x = tsum;
#pragma unroll
    for (int d = 1; d < 64; d <<= 1) { int y = __shfl_up(x, d); if (lane >= d) x += y; }
    if (lane == 63) wsum[wv] = x;
    __syncthreads();
    int wo = 0;
    for (int w = 0; w < wv; w++) wo += wsum[w];
    int tot = wsum[0] + wsum[1] + wsum[2] + wsum[3];
    int excl = runbase + wo + x - tsum;
    if (i + 0 < N) { rowptr[i + 0] = excl; cursor[i + 0] = excl; }
    if (i + 1 < N) { rowptr[i + 1] = excl + v0; cursor[i + 1] = excl + v0; }
    if (i + 2 < N) { rowptr[i + 2] = excl + v0 + v1; cursor[i + 2] = excl + v0 + v1; }
    if (i + 3 < N) { rowptr[i + 3] = excl + v0 + v1 + v2; cursor[i + 3] = excl + v0 + v1 + v2; }
    runbase += tot;
    __syncthreads();
  }
  if (t == 0) rowptr[N] = runbase;
}

// ---------------------------------------------------------------------------
// L2: conf U mono-scan
// ---------------------------------------------------------------------------
__global__ __launch_bounds__(256) void mega2_kernel(
    const float* __restrict__ emb, const unsigned short* __restrict__ PBc,
    const float* __restrict__ cb1, const float* __restrict__ cw2,
    const float* __restrict__ cb2, float* __restrict__ wec,
    const int* __restrict__ indeg, int* __restrict__ rowptr,
    int* __restrict__ cursor, int N, int GC) {
  __shared__ __align__(16) unsigned short astage[128 * 264];
  int b = blockIdx.x;
  if (b < GC) {
    conf_body(b, astage, emb, PBc, cb1, cw2, cb2, wec, N);
  } else {
    scan_body((int*)astage, indeg, rowptr, cursor, N);
  }
}

// ---------------------------------------------------------------------------
// L3: scatter edges into CSR (1 int atomic per edge)
// ---------------------------------------------------------------------------
__global__ void scatter_kernel(const int* __restrict__ ei, int* __restrict__ cursor,
                               int* __restrict__ csr, int E, int N) {
  int idx = blockIdx.x * 256 + threadIdx.x;
  if (idx >= E + N) return;
  int src, dst;
  if (idx < E) { src = ei[idx]; dst = ei[E + idx]; } else { src = dst = idx - E; }
  int pos = atomicAdd(&cursor[dst], 1);
  csr[pos] = src;
}

// ---------------------------------------------------------------------------
// lstm body (32 nodes, 512 threads). setprio(1) around MFMA clusters.
// ---------------------------------------------------------------------------
#define HB2 4352  // 32*136

__device__ __forceinline__ void lstm_body(
    int bL, unsigned char* smem,
    const float* __restrict__ pred, const unsigned char* __restrict__ PB1,
    const unsigned char* __restrict__ PB2,
    const float* __restrict__ bih0, const float* __restrict__ bhh0,
    const float* __restrict__ bih1, const float* __restrict__ bhh1,
    float* __restrict__ wtc, int N) {
  unsigned char* hb = smem;                       // 4*HB2
  unsigned char* xbuf = smem + 4 * HB2;           // 1280
  float* varsum = (float*)(smem + 4 * HB2 + 1280);  // 32 floats
  int tid = threadIdx.x;
  int base = bL * 32;
  for (int i = tid * 4; i < HB2; i += 2048) *(int*)&hb[3 * HB2 + i] = 0;  // h2[-1]=0
  for (int i = tid; i < 32 * 40; i += 512) {
    int nd = i / 40, o = i - nd * 40;
    float v = 0.f;
    if (o < 10 && base + nd < N) v = pred[(size_t)(base + nd) * NC + o];
    xbuf[i] = f2fp8(v);
  }
  if (tid < 32) varsum[tid] = 0.f;
  int wave = tid >> 6, lane = tid & 63, quad = lane >> 4, ln = lane & 15;
  float b0f[4], b1f[4];
#pragma unroll
  for (int g = 0; g < 4; g++) {
    int row = g * 128 + wave * 16 + ln;
    b0f[g] = bih0[row] + bhh0[row];
    b1f[g] = bih1[row] + bhh1[row];
  }
  long w1r[5][4], w2r[8][4];
#pragma unroll
  for (int ks = 0; ks < 5; ks++)
#pragma unroll
    for (int g = 0; g < 4; g++)
      w1r[ks][g] = *(const long*)(PB1 + (size_t)(((ks * 8 + wave) * 4 + g) * 64 + lane) * 8);
#pragma unroll
  for (int ks = 0; ks < 8; ks++)
#pragma unroll
    for (int g = 0; g < 4; g++)
      w2r[ks][g] = *(const long*)(PB2 + (size_t)(((ks * 8 + wave) * 4 + g) * 64 + lane) * 8);
  float c1[8], c2[8], s1[8], s2[8];
#pragma unroll
  for (int i = 0; i < 8; i++) { c1[i] = 0.f; c2[i] = 0.f; s1[i] = 0.f; s2[i] = 0.f; }
  const int hq = quad * 8;
  const int ucol = wave * 16 + ln;
  int arow[2], wrow[2];
#pragma unroll
  for (int mt = 0; mt < 2; mt++) {
    arow[mt] = (mt * 16 + ln) * 136 + hq;
    wrow[mt] = (mt * 16 + quad * 4) * 136 + ucol;
  }
  __syncthreads();  // xbuf ready
  long xa[2];
  xa[0] = *(const long*)&xbuf[ln * 40 + hq];
  xa[1] = *(const long*)&xbuf[(16 + ln) * 40 + hq];

  // ----- prime: phase1(t=0), h1 state = 0 -----
  {
    floatx4 acc[2][4];
#pragma unroll
    for (int mt = 0; mt < 2; mt++)
#pragma unroll
      for (int g = 0; g < 4; g++) acc[mt][g] = (floatx4){b0f[g], b0f[g], b0f[g], b0f[g]};
#pragma unroll
    for (int g = 0; g < 4; g++)
#pragma unroll
      for (int mt = 0; mt < 2; mt++) acc[mt][g] = mfma8(xa[mt], w1r[4][g], acc[mt][g]);
#pragma unroll
    for (int mt = 0; mt < 2; mt++)
#pragma unroll
      for (int r = 0; r < 4; r++) {
        int ci = mt * 4 + r;
        float ig = sig2(acc[mt][0][r]);
        float gg = tanh2(acc[mt][2][r]);
        float og = sig2(acc[mt][3][r]);
        float c = ig * gg;
        c1[ci] = c;
        hb[0 + wrow[mt] + r * 136] = f2fp8(og * tanh2(c));
      }
  }

#define LSTM_SEG(O1R, O1W, O2R, O2W, lastseg)                                    \
  {                                                                              \
    __syncthreads();                                                             \
    floatx4 acc[2][4];                                                           \
    _Pragma("unroll") for (int mt = 0; mt < 2; mt++)                             \
        _Pragma("unroll") for (int g = 0; g < 4; g++)                            \
            acc[mt][g] = (floatx4){b1f[g], b1f[g], b1f[g], b1f[g]};              \
    __builtin_amdgcn_s_setprio(1);                                               \
    _Pragma("unroll") for (int ks = 0; ks < 8; ks++) {                           \
      long a_[2];                                                                \
      if (ks < 4) {                                                              \
        _Pragma("unroll") for (int mt = 0; mt < 2; mt++)                         \
            a_[mt] = *(const long*)&hb[(O1R) + arow[mt] + ks * 32];              \
      } else {                                                                   \
        _Pragma("unroll") for (int mt = 0; mt < 2; mt++)                         \
            a_[mt] = *(const long*)&hb[(O2R) + arow[mt] + (ks - 4) * 32];        \
      }                                                                          \
      _Pragma("unroll") for (int g = 0; g < 4; g++)                              \
          _Pragma("unroll") for (int mt = 0; mt < 2; mt++)                       \
              acc[mt][g] = mfma8(a_[mt], w2r[ks][g], acc[mt][g]);                \
    }                                                                            \
    __builtin_amdgcn_s_setprio(0);                                               \
    _Pragma("unroll") for (int mt = 0; mt < 2; mt++)                             \
        _Pragma("unroll") for (int r = 0; r < 4; r++) {                          \
      int ci = mt * 4 + r;                                                       \
      float ig = sig2(acc[mt][0][r]);                                            \
      float fg = sig2(acc[mt][1][r]);                                            \
      float gg = tanh2(acc[mt][2][r]);                                           \
      float og = sig2(acc[mt][3][r]);                                            \
      float c = fg * c2[ci] + ig * gg;                                           \
      c2[ci] = c;                                                                \
      float h = og * tanh2(c);                                                   \
      s1[ci] += h;                                                               \
      s2[ci] += h * h;                                                           \
      hb[(O2W) + wrow[mt] + r * 136] = f2fp8(h);                                 \
    }                                                                            \
    if (!(lastseg)) {                                                            \
      _Pragma("unroll") for (int mt = 0; mt < 2; mt++)                           \
          _Pragma("unroll") for (int g = 0; g < 4; g++)                          \
              acc[mt][g] = (floatx4){b0f[g], b0f[g], b0f[g], b0f[g]};            \
      __builtin_amdgcn_s_setprio(1);                                             \
      _Pragma("unroll") for (int ks = 0; ks < 5; ks++) {                         \
        long a_[2];                                                              \
        if (ks < 4) {                                                            \
          _Pragma("unroll") for (int mt = 0; mt < 2; mt++)                       \
              a_[mt] = *(const long*)&hb[(O1R) + arow[mt] + ks * 32];            \
        } else {                                                                 \
          a_[0] = xa[0]; a_[1] = xa[1];                                          \
        }                                                                        \
        _Pragma("unroll") for (int g = 0; g < 4; g++)                            \
            _Pragma("unroll") for (int mt = 0; mt < 2; mt++)                     \
                acc[mt][g] = mfma8(a_[mt], w1r[ks][g], acc[mt][g]);              \
      }                                                                          \
      __builtin_amdgcn_s_setprio(0);                                             \
      _Pragma("unroll") for (int mt = 0; mt < 2; mt++)                           \
          _Pragma("unroll") for (int r = 0; r < 4; r++) {                        \
        int ci = mt * 4 + r;                                                     \
        float ig = sig2(acc[mt][0][r]);                                          \
        float fg = sig2(acc[mt][1][r]);                                          \
        float gg = tanh2(acc[mt][2][r]);                                         \
        float og = sig2(acc[mt][3][r]);                                          \
        float c = fg * c1[ci] + ig * gg;                                         \
        c1[ci] = c;                                                              \
        hb[(O1W) + wrow[mt] + r * 136] = f2fp8(og * tanh2(c));                   \
      }                                                                          \
    }                                                                            \
  }

  for (int tt = 0; tt < TSTEPS / 2; tt++) {
    LSTM_SEG(0, HB2, 3 * HB2, 2 * HB2, false);
    LSTM_SEG(HB2, 0, 2 * HB2, 3 * HB2, tt == TSTEPS / 2 - 1);
  }
#undef LSTM_SEG

#pragma unroll
  for (int mt = 0; mt < 2; mt++)
#pragma unroll
    for (int r = 0; r < 4; r++) {
      int ci = mt * 4 + r;
      float m = s1[ci] * (1.f / 12.f);
      float var = (s2[ci] - 12.f * m * m) * (1.f / 11.f);
      atomicAdd(&varsum[mt * 16 + quad * 4 + r], var);
    }
  __syncthreads();
  if (tid < 32 && base + tid < N)
    wtc[base + tid] = 1.f / (1.f + varsum[tid] * (1.f / 128.f));
}

// ---------------------------------------------------------------------------
// gather body: 16 lanes/node (head h = sub&3, parity par = sub>>2, 4-way).
// ---------------------------------------------------------------------------
__device__ __forceinline__ void gather_body(
    int bg, unsigned char* smem,
    const int* __restrict__ rowptr, const int* __restrict__ csr,
    const float* __restrict__ was, const float* __restrict__ wad,
    const float* __restrict__ wp12, const int* __restrict__ wlab,
    const int* __restrict__ outdeg, const float* __restrict__ gW,
    const float* __restrict__ gb, float* __restrict__ wgc,
    float* __restrict__ wag, int N) {
  float* sgW = (float*)smem;
  int tid = threadIdx.x;
  for (int i = tid; i < 400; i += 512) sgW[i] = gW[i];
  __syncthreads();
  int vgid = bg * 512 + tid;
  int node = vgid >> 4, sub = vgid & 15, h = sub & 3, par = sub >> 2;
  if (node >= N) return;
  int beg = rowptr[node], end = rowptr[node + 1];
  float ad = wad[(size_t)node * 4 + h];
  int mylab = wlab[node];
  float ssum = 0.f, cnt = 0.f;
  float z[10];
#pragma unroll
  for (int c = 0; c < 10; c++) z[c] = 0.f;
  for (int e = beg + par; e < end; e += 4) {
    int s = csr[e];
    float v = was[(size_t)s * 4 + h] + ad;
    float lr = v >= 0.f ? v : 0.2f * v;
    float ex = fexp2(LOG2E * lr);  // bounded logits: no max-sub needed
    ssum += ex;
    const float4* pp = (const float4*)(wp12 + (size_t)s * 12);
    float4 p0 = pp[0], p1 = pp[1], p2 = pp[2];
    z[0] += ex * p0.x; z[1] += ex * p0.y; z[2] += ex * p0.z; z[3] += ex * p0.w;
    z[4] += ex * p1.x; z[5] += ex * p1.y; z[6] += ex * p1.z; z[7] += ex * p1.w;
    z[8] += ex * p2.x; z[9] += ex * p2.y;
    cnt += (wlab[s] == mylab) ? 1.f : 0.f;
  }
  // combine 4 edge parities (lane bits 2,3)
  ssum += __shfl_xor(ssum, 4); ssum += __shfl_xor(ssum, 8);
  cnt  += __shfl_xor(cnt, 4);  cnt  += __shfl_xor(cnt, 8);
#pragma unroll
  for (int c = 0; c < 10; c++) { z[c] += __shfl_xor(z[c], 4); z[c] += __shfl_xor(z[c], 8); }
  float inv = 1.f / (ssum + 1e-16f);
  float gpart[10];
#pragma unroll
  for (int c = 0; c < 10; c++) {
    float t = 0.f;
#pragma unroll
    for (int k = 0; k < 10; k++) t += z[k] * sgW[k * 40 + h * 10 + c];
    gpart[c] = t * inv;
  }
  // head mean reduce (lane bits 0,1)
#pragma unroll
  for (int c = 0; c < 10; c++) {
    gpart[c] += __shfl_xor(gpart[c], 1);
    gpart[c] += __shfl_xor(gpart[c], 2);
  }
  if (sub == 0) {
    float num = 0.f, np2 = 0.f, ng2 = 0.f;
    const float* pn = wp12 + (size_t)node * 12;
#pragma unroll
    for (int c = 0; c < 10; c++) {
      float g = gpart[c] * 0.25f + gb[c];
      float p = pn[c];
      num += p * g;
      np2 += p * p;
      ng2 += g * g;
    }
    float den = fmaxf(sqrtf(np2) * sqrtf(ng2), 1e-8f);
    wgc[node] = (num / den + 1.f) * 0.5f;
    float dgv = (float)outdeg[node];
    wag[node] = cnt / (dgv + 1e-8f);
  }
}

// ---------------------------------------------------------------------------
// L4: lstm U gather_main, 1:1 interleave. __launch_bounds__(512,2): the bound
// under which lstm compiled spill-free (124-128 VGPR) for 3 rounds. (512,4)
// caused a 7 GB scratch-spill catastrophe in round 9 — do not raise the floor.
// ---------------------------------------------------------------------------
__global__ __launch_bounds__(512, 2) void mega4_kernel(
    const float* __restrict__ pred, const unsigned char* __restrict__ PB1,
    const unsigned char* __restrict__ PB2,
    const float* __restrict__ bih0, const float* __restrict__ bhh0,
    const float* __restrict__ bih1, const float* __restrict__ bhh1,
    float* __restrict__ wtc,
    const int* __restrict__ rowptr, const int* __restrict__ csr,
    const float* __restrict__ was, const float* __restrict__ wad,
    const float* __restrict__ wp12, const int* __restrict__ wlab,
    const int* __restrict__ outdeg, const float* __restrict__ gW,
    const float* __restrict__ gb, float* __restrict__ wgc, float* __restrict__ wag,
    int N, int GL, int GG) {
  __shared__ __align__(16) unsigned char smem[4 * HB2 + 1280 + 128];
  int b = blockIdx.x;
  int mn = GL < GG ? GL : GG, m2 = 2 * mn;
  int isL, idx;
  if (b < m2) { isL = !(b & 1); idx = b >> 1; }
  else { isL = (GL > GG) ? 1 : 0; idx = mn + (b - m2); }
  if (isL) {
    lstm_body(idx, smem, pred, PB1, PB2, bih0, bhh0, bih1, bhh1, wtc, N);
  } else {
    gather_body(idx, smem, rowptr, csr, was, wad, wp12, wlab, outdeg, gW, gb,
                wgc, wag, N);
  }
}

// ---------------------------------------------------------------------------
// L5: combine (only consumer of lstm's wtc)
// ---------------------------------------------------------------------------
__global__ void combine_kernel(const float* __restrict__ wmp,
                               const float* __restrict__ wec,
                               const float* __restrict__ wtc,
                               const float* __restrict__ wgc,
                               const float* __restrict__ wag,
                               float* __restrict__ out, int N) {
  int node = blockIdx.x * 256 + threadIdx.x;
  if (node >= N) return;
  float mp = wmp[node], ec = wec[node], tc = wtc[node], gc = wgc[node];
  float comb = 0.4f * mp + 0.2f * ec + 0.2f * tc + 0.2f * gc;
  bool mask = (comb > 0.85f) && (wag[node] >= 0.6f);
  out[(size_t)1 * N + node] = comb;
  out[(size_t)2 * N + node] = mask ? 1.f : 0.f;
  out[(size_t)4 * N + node] = ec;
  out[(size_t)5 * N + node] = tc;
  out[(size_t)6 * N + node] = gc;
}

// ---------------------------------------------------------------------------
extern "C" void kernel_launch(void* const* d_in, const int* in_sizes, int n_in,
                              void* d_out, int out_size, void* d_ws, size_t ws_size,
                              hipStream_t stream) {
  const float* emb  = (const float*)d_in[0];
  const float* pred = (const float*)d_in[1];
  const int*   ei   = (const int*)d_in[3];
  const float* cw1  = (const float*)d_in[4];
  const float* cb1  = (const float*)d_in[5];
  const float* cw2  = (const float*)d_in[6];
  const float* cb2  = (const float*)d_in[7];
  const float* wih0 = (const float*)d_in[8];
  const float* whh0 = (const float*)d_in[9];
  const float* bih0 = (const float*)d_in[10];
  const float* bhh0 = (const float*)d_in[11];
  const float* wih1 = (const float*)d_in[12];
  const float* whh1 = (const float*)d_in[13];
  const float* bih1 = (const float*)d_in[14];
  const float* bhh1 = (const float*)d_in[15];
  const float* gW   = (const float*)d_in[16];
  const float* gas  = (const float*)d_in[17];
  const float* gad  = (const float*)d_in[18];
  const float* gb   = (const float*)d_in[19];

  const int N = in_sizes[0] / HIDN;
  const int E = in_sizes[3] / 2;
  float* out = (float*)d_out;
  float* ws = (float*)d_ws;
  const size_t sN = (size_t)N;

  float* wp12   = ws;                         // 12N
  float* was    = ws + 12 * sN;               // 4N
  float* wad    = ws + 16 * sN;               // 4N
  int*   wlab   = (int*)(ws + 20 * sN);       // N
  float* wmp    = ws + 21 * sN;               // N
  float* wec    = ws + 22 * sN;               // N
  float* wtc    = ws + 23 * sN;               // N
  float* wgc    = ws + 24 * sN;               // N
  float* wag    = ws + 25 * sN;               // N
  int* indeg    = (int*)(ws + 26 * sN);       // N   <- memset region start
  int* outdeg   = (int*)(ws + 27 * sN);       // N   <- memset region end
  int* rowptr   = (int*)(ws + 28 * sN);       // N+1 (+pad)
  int* cursor   = (int*)(ws + 29 * sN) + 64;  // N
  int* csr      = (int*)(ws + 30 * sN) + 128; // E+N
  float* pbase  = ws + 31 * sN + 128 + E;
  unsigned char* PB1 = (unsigned char*)pbase;                  // 81920 B
  unsigned char* PB2 = (unsigned char*)(pbase + 20480);        // 131072 B
  unsigned short* PBc = (unsigned short*)(pbase + 53248);      // 32768 ushort

  hipMemsetAsync(indeg, 0, 2 * sN * sizeof(int), stream);

  // L1: probs U pack U hist
  int GP = (N + 255) / 256, GK = 512, GH = (E + N + 255) / 256;
  mega1_kernel<<<GP + GK + GH, 256, 0, stream>>>(
      pred, gW, gas, gad, out, wp12, was, wad, wlab, wmp,
      whh0, wih0, wih1, whh1, cw1, PB1, PB2, PBc,
      ei, indeg, outdeg, N, E, GP, GK);

  // L2: conf U mono-scan
  int GC = (N + 127) / 128;
  mega2_kernel<<<GC + 1, 256, 0, stream>>>(
      emb, PBc, cb1, cw2, cb2, wec, indeg, rowptr, cursor, N, GC);

  // L3: scatter
  int ne = E + N;
  scatter_kernel<<<(ne + 255) / 256, 256, 0, stream>>>(ei, cursor, csr, E, N);

  // L4: lstm U gather (1:1 interleave)
  int GL = (N + 31) / 32;
  int GG = (16 * N + 511) / 512;
  mega4_kernel<<<GL + GG, 512, 0, stream>>>(
      pred, PB1, PB2, bih0, bhh0, bih1, bhh1, wtc,
      rowptr, csr, was, wad, wp12, wlab, outdeg, gW, gb, wgc, wag,
      N, GL, GG);

  // L5: combine
  combine_kernel<<<(N + 255) / 256, 256, 0, stream>>>(wmp, wec, wtc, wgc, wag, out, N);
}

// Round 7
// 1582.859 us; speedup vs baseline: 2.4221x; 1.3520x over previous
//
#include <hip/hip_runtime.h>
#include <hip/hip_bf16.h>

// ============================================================================
// PseudoLabelGenerator: round 13 — third submission of the round-11 structure.
// Rounds 11/12 died to broker-level container failures (no compile error, no
// pass/fail adjudication). Full audit vs round 10 (last executed): every body
// here ran successfully there; workspace/LDS/launch patterns all within
// previously-executed envelopes. Structure:
//     L1: probs U pack U hist
//     L2: conf U mono-scan
//     L3: scatter
//     L4: gather (256-thr standalone, full occupancy, 16 lanes/node)
//     L5: lstm (512,2) with combine folded into its 32-thread tail
//   Rationale: lstm is structurally 1 block/CU (~190 regs/wave, weights must
//   be register-resident); co-scheduling gather under it starved gather's TLP
//   (round 10: 60us standalone -> 633us fused). Keep them separate.
// ============================================================================

#define HIDN 256
#define NC 10
#define TSTEPS 12
#define NHEADS 4
#define LH 128

typedef __attribute__((ext_vector_type(8))) short short8;
typedef __attribute__((ext_vector_type(4))) float floatx4;

__device__ __forceinline__ unsigned short f2bf(float x) {
  unsigned u = __float_as_uint(x);
  u = u + 0x7FFFu + ((u >> 16) & 1u);   // round-to-nearest-even
  return (unsigned short)(u >> 16);
}
__device__ __forceinline__ unsigned char f2fp8(float x) {
  return (unsigned char)(__builtin_amdgcn_cvt_pk_fp8_f32(x, 0.f, 0, false) & 0xff);
}
__device__ __forceinline__ float fexp2(float x) { return __builtin_amdgcn_exp2f(x); }
__device__ __forceinline__ float frcpf(float x) { return __builtin_amdgcn_rcpf(x); }
#define LOG2E 1.44269504f
__device__ __forceinline__ float sigf(float x) {
  return frcpf(1.0f + fexp2(-LOG2E * x));
}
__device__ __forceinline__ float sig2(float x) {
  return frcpf(1.f + fexp2(-LOG2E * x));
}
__device__ __forceinline__ float tanh2(float x) {
  return 1.f - 2.f * frcpf(1.f + fexp2((2.f * LOG2E) * x));
}
__device__ __forceinline__ floatx4 mfma16(short8 a, short8 b, floatx4 c) {
  return __builtin_amdgcn_mfma_f32_16x16x32_bf16(a, b, c, 0, 0, 0);
}
__device__ __forceinline__ floatx4 mfma8(long a, long b, floatx4 c) {
  return __builtin_amdgcn_mfma_f32_16x16x32_fp8_fp8(a, b, c, 0, 0, 0);
}

// ---------------------------------------------------------------------------
// bodies for L1: probs / pack / hist
// ---------------------------------------------------------------------------
__device__ __forceinline__ void probs_body(
    int bb, float* sgW, float* sgas, float* sgad,
    const float* __restrict__ pred, const float* __restrict__ gW,
    const float* __restrict__ gas, const float* __restrict__ gad,
    float* __restrict__ out, float* __restrict__ wp12,
    float* __restrict__ was, float* __restrict__ wad,
    int* __restrict__ wlab, float* __restrict__ wmp, int N) {
  int tid = threadIdx.x;
  for (int i = tid; i < 400; i += 256) sgW[i] = gW[i];
  if (tid < 40) { sgas[tid] = gas[tid]; sgad[tid] = gad[tid]; }
  __syncthreads();
  int node = bb * 256 + tid;
  if (node >= N) return;
  const float* pr = pred + (size_t)node * NC;
  float p[NC];
#pragma unroll
  for (int c = 0; c < NC; c++) p[c] = pr[c];
  float pm = p[0]; int arg = 0;
#pragma unroll
  for (int c = 1; c < NC; c++) if (p[c] > pm) { pm = p[c]; arg = c; }
  float s = 0.f, prb[NC];
#pragma unroll
  for (int c = 0; c < NC; c++) { prb[c] = __expf(p[c] - pm); s += prb[c]; }
  float inv = 1.f / s;
  float ent = 0.f;
#pragma unroll
  for (int c = 0; c < NC; c++) {
    prb[c] *= inv;
    ent -= prb[c] * __logf(prb[c] + 1e-8f);
  }
  float4* wp = (float4*)(wp12 + (size_t)node * 12);
  wp[0] = make_float4(prb[0], prb[1], prb[2], prb[3]);
  wp[1] = make_float4(prb[4], prb[5], prb[6], prb[7]);
  wp[2] = make_float4(prb[8], prb[9], 0.f, 0.f);
  out[node] = (float)arg;
  out[(size_t)3 * N + node] = inv;
  out[(size_t)7 * N + node] = ent * (1.f / 2.302585093f);
  wlab[node] = arg;
  wmp[node] = inv;
  float xv[40];
#pragma unroll
  for (int hc = 0; hc < 40; hc++) {
    float t = 0.f;
#pragma unroll
    for (int k = 0; k < NC; k++) t += prb[k] * sgW[k * 40 + hc];
    xv[hc] = t;
  }
#pragma unroll
  for (int h = 0; h < NHEADS; h++) {
    float as = 0.f, ad = 0.f;
#pragma unroll
    for (int c = 0; c < NC; c++) { as += xv[h * 10 + c] * sgas[h * 10 + c]; ad += xv[h * 10 + c] * sgad[h * 10 + c]; }
    was[(size_t)node * 4 + h] = as;
    wad[(size_t)node * 4 + h] = ad;
  }
}

__device__ __forceinline__ void pack_body(
    int bb, const float* __restrict__ whh0, const float* __restrict__ wih0,
    const float* __restrict__ wih1, const float* __restrict__ whh1,
    const float* __restrict__ cw1,
    unsigned char* __restrict__ PB1, unsigned char* __restrict__ PB2,
    unsigned short* __restrict__ PBc) {
  int idx = bb * 256 + threadIdx.x;
  if (idx < 81920) {  // PB1: 5ks*8w*4g*64*8 bytes
    int j = idx & 7, lane = (idx >> 3) & 63, rest = idx >> 9;
    int g = rest & 3, w = (rest >> 2) & 7, ks = rest >> 5;
    int k = ks * 32 + ((lane >> 4) << 3) + j;
    int u = w * 16 + (lane & 15), row = g * 128 + u;
    float val = 0.f;
    if (k < 128) val = whh0[row * 128 + k];
    else if (k < 138) val = wih0[row * 10 + (k - 128)];
    PB1[idx] = f2fp8(val);
  }
  if (idx < 131072) {  // PB2: 8ks*8w*4g*64*8 bytes
    int j = idx & 7, lane = (idx >> 3) & 63, rest = idx >> 9;
    int g = rest & 3, w = (rest >> 2) & 7, ks = rest >> 5;
    int k = ks * 32 + ((lane >> 4) << 3) + j;
    int u = w * 16 + (lane & 15), row = g * 128 + u;
    float val = (k < 128) ? wih1[row * 128 + k] : whh1[row * 128 + (k - 128)];
    PB2[idx] = f2fp8(val);
  }
  if (idx < 32768) {  // PBc: 8*8*64*8 bf16
    int j = idx & 7, lane = (idx >> 3) & 63, t2 = idx >> 9;
    int ti = t2 & 7, ks = t2 >> 3;
    int n = ti * 16 + (lane & 15);
    int k = ks * 32 + ((lane >> 4) << 3) + j;
    PBc[idx] = f2bf(cw1[n * 256 + k]);
  }
}

__device__ __forceinline__ void hist_body(
    int bb, const int* __restrict__ ei, int* __restrict__ indeg,
    int* __restrict__ outdeg, int E, int N) {
  int idx = bb * 256 + threadIdx.x;
  if (idx >= E + N) return;
  int src, dst;
  if (idx < E) { src = ei[idx]; dst = ei[E + idx]; } else { src = dst = idx - E; }
  atomicAdd(&indeg[dst], 1);
  atomicAdd(&outdeg[src], 1);
}

// ---------------------------------------------------------------------------
// L1: probs U pack U hist
// ---------------------------------------------------------------------------
__global__ __launch_bounds__(256) void mega1_kernel(
    const float* __restrict__ pred, const float* __restrict__ gW,
    const float* __restrict__ gas, const float* __restrict__ gad,
    float* __restrict__ out, float* __restrict__ wp12,
    float* __restrict__ was, float* __restrict__ wad,
    int* __restrict__ wlab, float* __restrict__ wmp,
    const float* __restrict__ whh0, const float* __restrict__ wih0,
    const float* __restrict__ wih1, const float* __restrict__ whh1,
    const float* __restrict__ cw1,
    unsigned char* __restrict__ PB1, unsigned char* __restrict__ PB2,
    unsigned short* __restrict__ PBc,
    const int* __restrict__ ei, int* __restrict__ indeg, int* __restrict__ outdeg,
    int N, int E, int GP, int GK) {
  __shared__ float sgW[400], sgas[40], sgad[40];
  int b = blockIdx.x;
  if (b < GP) {
    probs_body(b, sgW, sgas, sgad, pred, gW, gas, gad, out, wp12, was, wad, wlab, wmp, N);
  } else if (b < GP + GK) {
    pack_body(b - GP, whh0, wih0, wih1, whh1, cw1, PB1, PB2, PBc);
  } else {
    hist_body(b - GP - GK, ei, indeg, outdeg, E, N);
  }
}

// ---------------------------------------------------------------------------
// bodies for L2: conf / mono-scan
// ---------------------------------------------------------------------------
__device__ __forceinline__ void conf_body(
    int bb, unsigned short* astage,
    const float* __restrict__ emb, const unsigned short* __restrict__ PBc,
    const float* __restrict__ cb1, const float* __restrict__ cw2,
    const float* __restrict__ cb2, float* __restrict__ wec, int N) {
  int tid = threadIdx.x;
  int base = bb * 128;
  for (int i = tid * 4; i < 128 * 256; i += 1024) {
    int row = i >> 8, col = i & 255;
    float4 v = make_float4(0.f, 0.f, 0.f, 0.f);
    if (base + row < N) v = *(const float4*)(emb + (size_t)(base + row) * 256 + col);
    unsigned short* d = &astage[row * 264 + col];
    d[0] = f2bf(v.x); d[1] = f2bf(v.y); d[2] = f2bf(v.z); d[3] = f2bf(v.w);
  }
  __syncthreads();
  int wave = tid >> 6, lane = tid & 63, quad = lane >> 4, ln = lane & 15;
  float b1f[8], w2f[8];
#pragma unroll
  for (int t = 0; t < 8; t++) { b1f[t] = cb1[t * 16 + ln]; w2f[t] = cw2[t * 16 + ln]; }
  floatx4 acc[2][8];
#pragma unroll
  for (int mi = 0; mi < 2; mi++)
#pragma unroll
    for (int t = 0; t < 8; t++) acc[mi][t] = (floatx4){b1f[t], b1f[t], b1f[t], b1f[t]};
#pragma unroll
  for (int ks = 0; ks < 8; ks++) {
    short8 a0 = *(const short8*)&astage[(wave * 32 + ln) * 264 + ks * 32 + quad * 8];
    short8 a1 = *(const short8*)&astage[(wave * 32 + 16 + ln) * 264 + ks * 32 + quad * 8];
    const unsigned short* bp = PBc + (((size_t)(ks * 8) * 64 + lane) << 3);
#pragma unroll
    for (int t = 0; t < 8; t++) {
      short8 b = *(const short8*)(bp + (size_t)t * 512);
      acc[0][t] = mfma16(a0, b, acc[0][t]);
      acc[1][t] = mfma16(a1, b, acc[1][t]);
    }
  }
  float part[2][4];
#pragma unroll
  for (int mi = 0; mi < 2; mi++)
#pragma unroll
    for (int r = 0; r < 4; r++) {
      float t = 0.f;
#pragma unroll
      for (int ti = 0; ti < 8; ti++) t += fmaxf(acc[mi][ti][r], 0.f) * w2f[ti];
      part[mi][r] = t;
    }
#pragma unroll
  for (int off = 8; off >= 1; off >>= 1)
#pragma unroll
    for (int mi = 0; mi < 2; mi++)
#pragma unroll
      for (int r = 0; r < 4; r++) part[mi][r] += __shfl_xor(part[mi][r], off);
  if (ln == 0) {
    float b2 = cb2[0];
#pragma unroll
    for (int mi = 0; mi < 2; mi++)
#pragma unroll
      for (int r = 0; r < 4; r++) {
        int node = base + wave * 32 + mi * 16 + quad * 4 + r;
        if (node < N) wec[node] = sigf(part[mi][r] + b2);
      }
  }
}

// single-block exclusive scan of indeg -> rowptr + cursor (256 threads)
__device__ __forceinline__ void scan_body(
    int* wsum, const int* __restrict__ indeg, int* __restrict__ rowptr,
    int* __restrict__ cursor, int N) {
  int t = threadIdx.x;
  int lane = t & 63, wv = t >> 6;
  int runbase = 0;
  for (int c0 = 0; c0 < N; c0 += 1024) {
    int i = c0 + t * 4;
    int v0 = 0, v1 = 0, v2 = 0, v3 = 0;
    if (i + 0 < N) v0 = indeg[i + 0];
    if (i + 1 < N) v1 = indeg[i + 1];
    if (i + 2 < N) v2 = indeg[i + 2];
    if (i + 3 < N) v3 = indeg[i + 3];
    int tsum = v0 + v1 + v2 + v3;
    int x = tsum;
#pragma unroll
    for (int d = 1; d < 64; d <<= 1) { int y = __shfl_up(x, d); if (lane >= d) x += y; }
    if (lane == 63) wsum[wv] = x;
    __syncthreads();
    int wo = 0;
    for (int w = 0; w < wv; w++) wo += wsum[w];
    int tot = wsum[0] + wsum[1] + wsum[2] + wsum[3];
    int excl = runbase + wo + x - tsum;
    if (i + 0 < N) { rowptr[i + 0] = excl; cursor[i + 0] = excl; }
    if (i + 1 < N) { rowptr[i + 1] = excl + v0; cursor[i + 1] = excl + v0; }
    if (i + 2 < N) { rowptr[i + 2] = excl + v0 + v1; cursor[i + 2] = excl + v0 + v1; }
    if (i + 3 < N) { rowptr[i + 3] = excl + v0 + v1 + v2; cursor[i + 3] = excl + v0 + v1 + v2; }
    runbase += tot;
    __syncthreads();
  }
  if (t == 0) rowptr[N] = runbase;
}

// ---------------------------------------------------------------------------
// L2: conf U mono-scan
// ---------------------------------------------------------------------------
__global__ __launch_bounds__(256) void mega2_kernel(
    const float* __restrict__ emb, const unsigned short* __restrict__ PBc,
    const float* __restrict__ cb1, const float* __restrict__ cw2,
    const float* __restrict__ cb2, float* __restrict__ wec,
    const int* __restrict__ indeg, int* __restrict__ rowptr,
    int* __restrict__ cursor, int N, int GC) {
  __shared__ __align__(16) unsigned short astage[128 * 264];
  int b = blockIdx.x;
  if (b < GC) {
    conf_body(b, astage, emb, PBc, cb1, cw2, cb2, wec, N);
  } else {
    scan_body((int*)astage, indeg, rowptr, cursor, N);
  }
}

// ---------------------------------------------------------------------------
// L3: scatter edges into CSR (1 int atomic per edge)
// ---------------------------------------------------------------------------
__global__ void scatter_kernel(const int* __restrict__ ei, int* __restrict__ cursor,
                               int* __restrict__ csr, int E, int N) {
  int idx = blockIdx.x * 256 + threadIdx.x;
  if (idx >= E + N) return;
  int src, dst;
  if (idx < E) { src = ei[idx]; dst = ei[E + idx]; } else { src = dst = idx - E; }
  int pos = atomicAdd(&cursor[dst], 1);
  csr[pos] = src;
}

// ---------------------------------------------------------------------------
// L4: gather — standalone, 256 threads, full occupancy (the TLP regime it
// needs). 16 lanes/node: head h = sub&3, parity par = sub>>2 (4-way).
// Single pass (bounded logits -> no segment-max; softmax shift-invariant).
// ---------------------------------------------------------------------------
__global__ __launch_bounds__(256) void gather_kernel(
    const int* __restrict__ rowptr, const int* __restrict__ csr,
    const float* __restrict__ was, const float* __restrict__ wad,
    const float* __restrict__ wp12, const int* __restrict__ wlab,
    const int* __restrict__ outdeg, const float* __restrict__ gW,
    const float* __restrict__ gb, float* __restrict__ wgc,
    float* __restrict__ wag, int N) {
  __shared__ float sgW[400];
  int tid = threadIdx.x;
  for (int i = tid; i < 400; i += 256) sgW[i] = gW[i];
  __syncthreads();
  int vgid = blockIdx.x * 256 + tid;
  int node = vgid >> 4, sub = vgid & 15, h = sub & 3, par = sub >> 2;
  if (node >= N) return;
  int beg = rowptr[node], end = rowptr[node + 1];
  float ad = wad[(size_t)node * 4 + h];
  int mylab = wlab[node];
  float ssum = 0.f, cnt = 0.f;
  float z[10];
#pragma unroll
  for (int c = 0; c < 10; c++) z[c] = 0.f;
  for (int e = beg + par; e < end; e += 4) {
    int s = csr[e];
    float v = was[(size_t)s * 4 + h] + ad;
    float lr = v >= 0.f ? v : 0.2f * v;
    float ex = fexp2(LOG2E * lr);
    ssum += ex;
    const float4* pp = (const float4*)(wp12 + (size_t)s * 12);
    float4 p0 = pp[0], p1 = pp[1], p2 = pp[2];
    z[0] += ex * p0.x; z[1] += ex * p0.y; z[2] += ex * p0.z; z[3] += ex * p0.w;
    z[4] += ex * p1.x; z[5] += ex * p1.y; z[6] += ex * p1.z; z[7] += ex * p1.w;
    z[8] += ex * p2.x; z[9] += ex * p2.y;
    cnt += (wlab[s] == mylab) ? 1.f : 0.f;
  }
  // combine 4 edge parities (lane bits 2,3)
  ssum += __shfl_xor(ssum, 4); ssum += __shfl_xor(ssum, 8);
  cnt  += __shfl_xor(cnt, 4);  cnt  += __shfl_xor(cnt, 8);
#pragma unroll
  for (int c = 0; c < 10; c++) { z[c] += __shfl_xor(z[c], 4); z[c] += __shfl_xor(z[c], 8); }
  float inv = 1.f / (ssum + 1e-16f);
  float gpart[10];
#pragma unroll
  for (int c = 0; c < 10; c++) {
    float t = 0.f;
#pragma unroll
    for (int k = 0; k < 10; k++) t += z[k] * sgW[k * 40 + h * 10 + c];
    gpart[c] = t * inv;
  }
  // head mean reduce (lane bits 0,1)
#pragma unroll
  for (int c = 0; c < 10; c++) {
    gpart[c] += __shfl_xor(gpart[c], 1);
    gpart[c] += __shfl_xor(gpart[c], 2);
  }
  if (sub == 0) {
    float num = 0.f, np2 = 0.f, ng2 = 0.f;
    const float* pn = wp12 + (size_t)node * 12;
#pragma unroll
    for (int c = 0; c < 10; c++) {
      float g = gpart[c] * 0.25f + gb[c];
      float p = pn[c];
      num += p * g;
      np2 += p * p;
      ng2 += g * g;
    }
    float den = fmaxf(sqrtf(np2) * sqrtf(ng2), 1e-8f);
    wgc[node] = (num / den + 1.f) * 0.5f;
    float dgv = (float)outdeg[node];
    wag[node] = cnt / (dgv + 1e-8f);
  }
}

// ---------------------------------------------------------------------------
// L5: fused 2-layer LSTM, fp8, 32 nodes/block, 512 threads (8 waves).
// Exact round-8 proven config: (512,2), no setprio, weights register-resident.
// Combine folded into the 32-thread tail (reads wmp/wec/wgc/wag, writes out).
// ---------------------------------------------------------------------------
#define HB2 4352  // 32*136

__global__ __launch_bounds__(512, 2) void lstm_kernel(
    const float* __restrict__ pred, const unsigned char* __restrict__ PB1,
    const unsigned char* __restrict__ PB2,
    const float* __restrict__ bih0, const float* __restrict__ bhh0,
    const float* __restrict__ bih1, const float* __restrict__ bhh1,
    const float* __restrict__ wmp, const float* __restrict__ wec,
    const float* __restrict__ wgc, const float* __restrict__ wag,
    float* __restrict__ out, int N) {
  __shared__ __align__(16) unsigned char hb[4 * HB2];  // h1: [0],[HB2]; h2: [2HB2],[3HB2]
  __shared__ __align__(16) unsigned char xbuf[32 * 40];
  __shared__ float varsum[32];
  int tid = threadIdx.x;
  int base = blockIdx.x * 32;
  for (int i = tid * 4; i < HB2; i += 2048) *(int*)&hb[3 * HB2 + i] = 0;  // h2[-1]=0
  for (int i = tid; i < 32 * 40; i += 512) {
    int nd = i / 40, o = i - nd * 40;
    float v = 0.f;
    if (o < 10 && base + nd < N) v = pred[(size_t)(base + nd) * NC + o];
    xbuf[i] = f2fp8(v);
  }
  if (tid < 32) varsum[tid] = 0.f;
  int wave = tid >> 6, lane = tid & 63, quad = lane >> 4, ln = lane & 15;
  float b0f[4], b1f[4];
#pragma unroll
  for (int g = 0; g < 4; g++) {
    int row = g * 128 + wave * 16 + ln;
    b0f[g] = bih0[row] + bhh0[row];
    b1f[g] = bih1[row] + bhh1[row];
  }
  long w1r[5][4], w2r[8][4];
#pragma unroll
  for (int ks = 0; ks < 5; ks++)
#pragma unroll
    for (int g = 0; g < 4; g++)
      w1r[ks][g] = *(const long*)(PB1 + (size_t)(((ks * 8 + wave) * 4 + g) * 64 + lane) * 8);
#pragma unroll
  for (int ks = 0; ks < 8; ks++)
#pragma unroll
    for (int g = 0; g < 4; g++)
      w2r[ks][g] = *(const long*)(PB2 + (size_t)(((ks * 8 + wave) * 4 + g) * 64 + lane) * 8);
  float c1[8], c2[8], s1[8], s2[8];
#pragma unroll
  for (int i = 0; i < 8; i++) { c1[i] = 0.f; c2[i] = 0.f; s1[i] = 0.f; s2[i] = 0.f; }
  const int hq = quad * 8;
  const int ucol = wave * 16 + ln;
  int arow[2], wrow[2];
#pragma unroll
  for (int mt = 0; mt < 2; mt++) {
    arow[mt] = (mt * 16 + ln) * 136 + hq;
    wrow[mt] = (mt * 16 + quad * 4) * 136 + ucol;
  }
  __syncthreads();  // xbuf ready
  long xa[2];
  xa[0] = *(const long*)&xbuf[ln * 40 + hq];
  xa[1] = *(const long*)&xbuf[(16 + ln) * 40 + hq];

  // ----- prime: phase1(t=0), h1 state = 0 -----
  {
    floatx4 acc[2][4];
#pragma unroll
    for (int mt = 0; mt < 2; mt++)
#pragma unroll
      for (int g = 0; g < 4; g++) acc[mt][g] = (floatx4){b0f[g], b0f[g], b0f[g], b0f[g]};
#pragma unroll
    for (int g = 0; g < 4; g++)
#pragma unroll
      for (int mt = 0; mt < 2; mt++) acc[mt][g] = mfma8(xa[mt], w1r[4][g], acc[mt][g]);
#pragma unroll
    for (int mt = 0; mt < 2; mt++)
#pragma unroll
      for (int r = 0; r < 4; r++) {
        int ci = mt * 4 + r;
        float ig = sig2(acc[mt][0][r]);
        float gg = tanh2(acc[mt][2][r]);
        float og = sig2(acc[mt][3][r]);
        float c = ig * gg;
        c1[ci] = c;
        hb[0 + wrow[mt] + r * 136] = f2fp8(og * tanh2(c));
      }
  }

#define LSTM_SEG(O1R, O1W, O2R, O2W, lastseg)                                    \
  {                                                                              \
    __syncthreads();                                                             \
    floatx4 acc[2][4];                                                           \
    _Pragma("unroll") for (int mt = 0; mt < 2; mt++)                             \
        _Pragma("unroll") for (int g = 0; g < 4; g++)                            \
            acc[mt][g] = (floatx4){b1f[g], b1f[g], b1f[g], b1f[g]};              \
    _Pragma("unroll") for (int ks = 0; ks < 8; ks++) {                           \
      long a_[2];                                                                \
      if (ks < 4) {                                                              \
        _Pragma("unroll") for (int mt = 0; mt < 2; mt++)                         \
            a_[mt] = *(const long*)&hb[(O1R) + arow[mt] + ks * 32];              \
      } else {                                                                   \
        _Pragma("unroll") for (int mt = 0; mt < 2; mt++)                         \
            a_[mt] = *(const long*)&hb[(O2R) + arow[mt] + (ks - 4) * 32];        \
      }                                                                          \
      _Pragma("unroll") for (int g = 0; g < 4; g++)                              \
          _Pragma("unroll") for (int mt = 0; mt < 2; mt++)                       \
              acc[mt][g] = mfma8(a_[mt], w2r[ks][g], acc[mt][g]);                \
    }                                                                            \
    _Pragma("unroll") for (int mt = 0; mt < 2; mt++)                             \
        _Pragma("unroll") for (int r = 0; r < 4; r++) {                          \
      int ci = mt * 4 + r;                                                       \
      float ig = sig2(acc[mt][0][r]);                                            \
      float fg = sig2(acc[mt][1][r]);                                            \
      float gg = tanh2(acc[mt][2][r]);                                           \
      float og = sig2(acc[mt][3][r]);                                            \
      float c = fg * c2[ci] + ig * gg;                                           \
      c2[ci] = c;                                                                \
      float h = og * tanh2(c);                                                   \
      s1[ci] += h;                                                               \
      s2[ci] += h * h;                                                           \
      hb[(O2W) + wrow[mt] + r * 136] = f2fp8(h);                                 \
    }                                                                            \
    if (!(lastseg)) {                                                            \
      _Pragma("unroll") for (int mt = 0; mt < 2; mt++)                           \
          _Pragma("unroll") for (int g = 0; g < 4; g++)                          \
              acc[mt][g] = (floatx4){b0f[g], b0f[g], b0f[g], b0f[g]};            \
      _Pragma("unroll") for (int ks = 0; ks < 5; ks++) {                         \
        long a_[2];                                                              \
        if (ks < 4) {                                                            \
          _Pragma("unroll") for (int mt = 0; mt < 2; mt++)                       \
              a_[mt] = *(const long*)&hb[(O1R) + arow[mt] + ks * 32];            \
        } else {                                                                 \
          a_[0] = xa[0]; a_[1] = xa[1];                                          \
        }                                                                        \
        _Pragma("unroll") for (int g = 0; g < 4; g++)                            \
            _Pragma("unroll") for (int mt = 0; mt < 2; mt++)                     \
                acc[mt][g] = mfma8(a_[mt], w1r[ks][g], acc[mt][g]);              \
      }                                                                          \
      _Pragma("unroll") for (int mt = 0; mt < 2; mt++)                           \
          _Pragma("unroll") for (int r = 0; r < 4; r++) {                        \
        int ci = mt * 4 + r;                                                     \
        float ig = sig2(acc[mt][0][r]);                                          \
        float fg = sig2(acc[mt][1][r]);                                          \
        float gg = tanh2(acc[mt][2][r]);                                         \
        float og = sig2(acc[mt][3][r]);                                          \
        float c = fg * c1[ci] + ig * gg;                                         \
        c1[ci] = c;                                                              \
        hb[(O1W) + wrow[mt] + r * 136] = f2fp8(og * tanh2(c));                   \
      }                                                                          \
    }                                                                            \
  }

  for (int tt = 0; tt < TSTEPS / 2; tt++) {
    LSTM_SEG(0, HB2, 3 * HB2, 2 * HB2, false);
    LSTM_SEG(HB2, 0, 2 * HB2, 3 * HB2, tt == TSTEPS / 2 - 1);
  }
#undef LSTM_SEG

  // variance (ddof=1) per (node,unit), summed over 128 units via LDS atomics
#pragma unroll
  for (int mt = 0; mt < 2; mt++)
#pragma unroll
    for (int r = 0; r < 4; r++) {
      int ci = mt * 4 + r;
      float m = s1[ci] * (1.f / 12.f);
      float var = (s2[ci] - 12.f * m * m) * (1.f / 11.f);
      atomicAdd(&varsum[mt * 16 + quad * 4 + r], var);
    }
  __syncthreads();
  // fused combine tail (only consumer of tc; wmp/wec/wgc/wag all ready)
  if (tid < 32 && base + tid < N) {
    int node = base + tid;
    float tc = 1.f / (1.f + varsum[tid] * (1.f / 128.f));
    float mp = wmp[node], ec = wec[node], gc = wgc[node];
    float comb = 0.4f * mp + 0.2f * ec + 0.2f * tc + 0.2f * gc;
    bool mask = (comb > 0.85f) && (wag[node] >= 0.6f);
    out[(size_t)1 * N + node] = comb;
    out[(size_t)2 * N + node] = mask ? 1.f : 0.f;
    out[(size_t)4 * N + node] = ec;
    out[(size_t)5 * N + node] = tc;
    out[(size_t)6 * N + node] = gc;
  }
}

// ---------------------------------------------------------------------------
extern "C" void kernel_launch(void* const* d_in, const int* in_sizes, int n_in,
                              void* d_out, int out_size, void* d_ws, size_t ws_size,
                              hipStream_t stream) {
  const float* emb  = (const float*)d_in[0];
  const float* pred = (const float*)d_in[1];
  const int*   ei   = (const int*)d_in[3];
  const float* cw1  = (const float*)d_in[4];
  const float* cb1  = (const float*)d_in[5];
  const float* cw2  = (const float*)d_in[6];
  const float* cb2  = (const float*)d_in[7];
  const float* wih0 = (const float*)d_in[8];
  const float* whh0 = (const float*)d_in[9];
  const float* bih0 = (const float*)d_in[10];
  const float* bhh0 = (const float*)d_in[11];
  const float* wih1 = (const float*)d_in[12];
  const float* whh1 = (const float*)d_in[13];
  const float* bih1 = (const float*)d_in[14];
  const float* bhh1 = (const float*)d_in[15];
  const float* gW   = (const float*)d_in[16];
  const float* gas  = (const float*)d_in[17];
  const float* gad  = (const float*)d_in[18];
  const float* gb   = (const float*)d_in[19];

  const int N = in_sizes[0] / HIDN;
  const int E = in_sizes[3] / 2;
  float* out = (float*)d_out;
  float* ws = (float*)d_ws;
  const size_t sN = (size_t)N;

  float* wp12   = ws;                         // 12N
  float* was    = ws + 12 * sN;               // 4N
  float* wad    = ws + 16 * sN;               // 4N
  int*   wlab   = (int*)(ws + 20 * sN);       // N
  float* wmp    = ws + 21 * sN;               // N
  float* wec    = ws + 22 * sN;               // N
  float* wgc    = ws + 24 * sN;               // N
  float* wag    = ws + 25 * sN;               // N
  int* indeg    = (int*)(ws + 26 * sN);       // N   <- memset region start
  int* outdeg   = (int*)(ws + 27 * sN);       // N   <- memset region end
  int* rowptr   = (int*)(ws + 28 * sN);       // N+1 (+pad)
  int* cursor   = (int*)(ws + 29 * sN) + 64;  // N
  int* csr      = (int*)(ws + 30 * sN) + 128; // E+N
  float* pbase  = ws + 31 * sN + 128 + E;
  unsigned char* PB1 = (unsigned char*)pbase;                  // 81920 B
  unsigned char* PB2 = (unsigned char*)(pbase + 20480);        // 131072 B
  unsigned short* PBc = (unsigned short*)(pbase + 53248);      // 32768 ushort

  hipMemsetAsync(indeg, 0, 2 * sN * sizeof(int), stream);

  // L1: probs U pack U hist
  int GP = (N + 255) / 256, GK = 512, GH = (E + N + 255) / 256;
  mega1_kernel<<<GP + GK + GH, 256, 0, stream>>>(
      pred, gW, gas, gad, out, wp12, was, wad, wlab, wmp,
      whh0, wih0, wih1, whh1, cw1, PB1, PB2, PBc,
      ei, indeg, outdeg, N, E, GP, GK);

  // L2: conf U mono-scan
  int GC = (N + 127) / 128;
  mega2_kernel<<<GC + 1, 256, 0, stream>>>(
      emb, PBc, cb1, cw2, cb2, wec, indeg, rowptr, cursor, N, GC);

  // L3: scatter
  int ne = E + N;
  scatter_kernel<<<(ne + 255) / 256, 256, 0, stream>>>(ei, cursor, csr, E, N);

  // L4: gather (standalone, full occupancy)
  gather_kernel<<<(16 * N + 255) / 256, 256, 0, stream>>>(
      rowptr, csr, was, wad, wp12, wlab, outdeg, gW, gb, wgc, wag, N);

  // L5: lstm + fused combine tail
  lstm_kernel<<<(N + 31) / 32, 512, 0, stream>>>(
      pred, PB1, PB2, bih0, bhh0, bih1, bhh1, wmp, wec, wgc, wag, out, N);
}

// Round 8
// 1411.575 us; speedup vs baseline: 2.7160x; 1.1213x over previous
//
#include <hip/hip_runtime.h>
#include <hip/hip_bf16.h>

// ============================================================================
// PseudoLabelGenerator: round 14 — rank-based CSR build (atomic-diet) +
// de-fused tail launches for per-kernel attribution.
//   Tail (probs+pack+hist+conf+scan+scatter) ≈ 776us, ~5x over its bandwidth
//   estimate -> suspect device-scope atomics. Changes:
//   1. rankhist: r = atomicAdd(indeg[dst]) RETURNS edge's rank in its bin;
//      store erank[e]. scatter then becomes csr[rowptr[dst]+erank[e]] = src
//      -> ZERO atomics in scatter (was 3.3M with-return round-trips).
//   2. probs/pack/rankhist as separate launches -> top-5 table shows the
//      tail's true split next round.
//   3. lstm (proven 722us config), gather, conf U scan: unchanged.
// ============================================================================

#define HIDN 256
#define NC 10
#define TSTEPS 12
#define NHEADS 4
#define LH 128

typedef __attribute__((ext_vector_type(8))) short short8;
typedef __attribute__((ext_vector_type(4))) float floatx4;

__device__ __forceinline__ unsigned short f2bf(float x) {
  unsigned u = __float_as_uint(x);
  u = u + 0x7FFFu + ((u >> 16) & 1u);   // round-to-nearest-even
  return (unsigned short)(u >> 16);
}
__device__ __forceinline__ unsigned char f2fp8(float x) {
  return (unsigned char)(__builtin_amdgcn_cvt_pk_fp8_f32(x, 0.f, 0, false) & 0xff);
}
__device__ __forceinline__ float fexp2(float x) { return __builtin_amdgcn_exp2f(x); }
__device__ __forceinline__ float frcpf(float x) { return __builtin_amdgcn_rcpf(x); }
#define LOG2E 1.44269504f
__device__ __forceinline__ float sigf(float x) {
  return frcpf(1.0f + fexp2(-LOG2E * x));
}
__device__ __forceinline__ float sig2(float x) {
  return frcpf(1.f + fexp2(-LOG2E * x));
}
__device__ __forceinline__ float tanh2(float x) {
  return 1.f - 2.f * frcpf(1.f + fexp2((2.f * LOG2E) * x));
}
__device__ __forceinline__ floatx4 mfma16(short8 a, short8 b, floatx4 c) {
  return __builtin_amdgcn_mfma_f32_16x16x32_bf16(a, b, c, 0, 0, 0);
}
__device__ __forceinline__ floatx4 mfma8(long a, long b, floatx4 c) {
  return __builtin_amdgcn_mfma_f32_16x16x32_fp8_fp8(a, b, c, 0, 0, 0);
}

// ---------------------------------------------------------------------------
// K-probs: per-node softmax / argmax / entropy + GAT attention scalars
// ---------------------------------------------------------------------------
__global__ __launch_bounds__(256) void probs_kernel(
    const float* __restrict__ pred, const float* __restrict__ gW,
    const float* __restrict__ gas, const float* __restrict__ gad,
    float* __restrict__ out, float* __restrict__ wp12,
    float* __restrict__ was, float* __restrict__ wad,
    int* __restrict__ wlab, float* __restrict__ wmp, int N) {
  __shared__ float sgW[400], sgas[40], sgad[40];
  int tid = threadIdx.x;
  for (int i = tid; i < 400; i += 256) sgW[i] = gW[i];
  if (tid < 40) { sgas[tid] = gas[tid]; sgad[tid] = gad[tid]; }
  __syncthreads();
  int node = blockIdx.x * 256 + tid;
  if (node >= N) return;
  const float* pr = pred + (size_t)node * NC;
  float p[NC];
#pragma unroll
  for (int c = 0; c < NC; c++) p[c] = pr[c];
  float pm = p[0]; int arg = 0;
#pragma unroll
  for (int c = 1; c < NC; c++) if (p[c] > pm) { pm = p[c]; arg = c; }
  float s = 0.f, prb[NC];
#pragma unroll
  for (int c = 0; c < NC; c++) { prb[c] = __expf(p[c] - pm); s += prb[c]; }
  float inv = 1.f / s;
  float ent = 0.f;
#pragma unroll
  for (int c = 0; c < NC; c++) {
    prb[c] *= inv;
    ent -= prb[c] * __logf(prb[c] + 1e-8f);
  }
  float4* wp = (float4*)(wp12 + (size_t)node * 12);
  wp[0] = make_float4(prb[0], prb[1], prb[2], prb[3]);
  wp[1] = make_float4(prb[4], prb[5], prb[6], prb[7]);
  wp[2] = make_float4(prb[8], prb[9], 0.f, 0.f);
  out[node] = (float)arg;
  out[(size_t)3 * N + node] = inv;
  out[(size_t)7 * N + node] = ent * (1.f / 2.302585093f);
  wlab[node] = arg;
  wmp[node] = inv;
  float xv[40];
#pragma unroll
  for (int hc = 0; hc < 40; hc++) {
    float t = 0.f;
#pragma unroll
    for (int k = 0; k < NC; k++) t += prb[k] * sgW[k * 40 + hc];
    xv[hc] = t;
  }
#pragma unroll
  for (int h = 0; h < NHEADS; h++) {
    float as = 0.f, ad = 0.f;
#pragma unroll
    for (int c = 0; c < NC; c++) { as += xv[h * 10 + c] * sgas[h * 10 + c]; ad += xv[h * 10 + c] * sgad[h * 10 + c]; }
    was[(size_t)node * 4 + h] = as;
    wad[(size_t)node * 4 + h] = ad;
  }
}

// ---------------------------------------------------------------------------
// K-pack: weight packing (layout unchanged)
// ---------------------------------------------------------------------------
__global__ __launch_bounds__(256) void pack_kernel(
    const float* __restrict__ whh0, const float* __restrict__ wih0,
    const float* __restrict__ wih1, const float* __restrict__ whh1,
    const float* __restrict__ cw1,
    unsigned char* __restrict__ PB1, unsigned char* __restrict__ PB2,
    unsigned short* __restrict__ PBc) {
  int idx = blockIdx.x * 256 + threadIdx.x;
  if (idx < 81920) {  // PB1: 5ks*8w*4g*64*8 bytes
    int j = idx & 7, lane = (idx >> 3) & 63, rest = idx >> 9;
    int g = rest & 3, w = (rest >> 2) & 7, ks = rest >> 5;
    int k = ks * 32 + ((lane >> 4) << 3) + j;
    int u = w * 16 + (lane & 15), row = g * 128 + u;
    float val = 0.f;
    if (k < 128) val = whh0[row * 128 + k];
    else if (k < 138) val = wih0[row * 10 + (k - 128)];
    PB1[idx] = f2fp8(val);
  }
  if (idx < 131072) {  // PB2: 8ks*8w*4g*64*8 bytes
    int j = idx & 7, lane = (idx >> 3) & 63, rest = idx >> 9;
    int g = rest & 3, w = (rest >> 2) & 7, ks = rest >> 5;
    int k = ks * 32 + ((lane >> 4) << 3) + j;
    int u = w * 16 + (lane & 15), row = g * 128 + u;
    float val = (k < 128) ? wih1[row * 128 + k] : whh1[row * 128 + (k - 128)];
    PB2[idx] = f2fp8(val);
  }
  if (idx < 32768) {  // PBc: 8*8*64*8 bf16
    int j = idx & 7, lane = (idx >> 3) & 63, t2 = idx >> 9;
    int ti = t2 & 7, ks = t2 >> 3;
    int n = ti * 16 + (lane & 15);
    int k = ks * 32 + ((lane >> 4) << 3) + j;
    PBc[idx] = f2bf(cw1[n * 256 + k]);
  }
}

// ---------------------------------------------------------------------------
// K-rankhist: degree histogram; indeg atomic's RETURN = edge's rank in its
// destination bin (stored to erank, coalesced). outdeg: no-return atomic.
// ---------------------------------------------------------------------------
__global__ void rankhist_kernel(const int* __restrict__ ei, int* __restrict__ indeg,
                                int* __restrict__ outdeg, int* __restrict__ erank,
                                int E, int N) {
  int idx = blockIdx.x * 256 + threadIdx.x;
  if (idx >= E + N) return;
  int src, dst;
  if (idx < E) { src = ei[idx]; dst = ei[E + idx]; } else { src = dst = idx - E; }
  int r = atomicAdd(&indeg[dst], 1);
  atomicAdd(&outdeg[src], 1);
  erank[idx] = r;
}

// ---------------------------------------------------------------------------
// conf body + mono-scan body, fused (scan hides under conf)
// ---------------------------------------------------------------------------
__device__ __forceinline__ void conf_body(
    int bb, unsigned short* astage,
    const float* __restrict__ emb, const unsigned short* __restrict__ PBc,
    const float* __restrict__ cb1, const float* __restrict__ cw2,
    const float* __restrict__ cb2, float* __restrict__ wec, int N) {
  int tid = threadIdx.x;
  int base = bb * 128;
  for (int i = tid * 4; i < 128 * 256; i += 1024) {
    int row = i >> 8, col = i & 255;
    float4 v = make_float4(0.f, 0.f, 0.f, 0.f);
    if (base + row < N) v = *(const float4*)(emb + (size_t)(base + row) * 256 + col);
    unsigned short* d = &astage[row * 264 + col];
    d[0] = f2bf(v.x); d[1] = f2bf(v.y); d[2] = f2bf(v.z); d[3] = f2bf(v.w);
  }
  __syncthreads();
  int wave = tid >> 6, lane = tid & 63, quad = lane >> 4, ln = lane & 15;
  float b1f[8], w2f[8];
#pragma unroll
  for (int t = 0; t < 8; t++) { b1f[t] = cb1[t * 16 + ln]; w2f[t] = cw2[t * 16 + ln]; }
  floatx4 acc[2][8];
#pragma unroll
  for (int mi = 0; mi < 2; mi++)
#pragma unroll
    for (int t = 0; t < 8; t++) acc[mi][t] = (floatx4){b1f[t], b1f[t], b1f[t], b1f[t]};
#pragma unroll
  for (int ks = 0; ks < 8; ks++) {
    short8 a0 = *(const short8*)&astage[(wave * 32 + ln) * 264 + ks * 32 + quad * 8];
    short8 a1 = *(const short8*)&astage[(wave * 32 + 16 + ln) * 264 + ks * 32 + quad * 8];
    const unsigned short* bp = PBc + (((size_t)(ks * 8) * 64 + lane) << 3);
#pragma unroll
    for (int t = 0; t < 8; t++) {
      short8 b = *(const short8*)(bp + (size_t)t * 512);
      acc[0][t] = mfma16(a0, b, acc[0][t]);
      acc[1][t] = mfma16(a1, b, acc[1][t]);
    }
  }
  float part[2][4];
#pragma unroll
  for (int mi = 0; mi < 2; mi++)
#pragma unroll
    for (int r = 0; r < 4; r++) {
      float t = 0.f;
#pragma unroll
      for (int ti = 0; ti < 8; ti++) t += fmaxf(acc[mi][ti][r], 0.f) * w2f[ti];
      part[mi][r] = t;
    }
#pragma unroll
  for (int off = 8; off >= 1; off >>= 1)
#pragma unroll
    for (int mi = 0; mi < 2; mi++)
#pragma unroll
      for (int r = 0; r < 4; r++) part[mi][r] += __shfl_xor(part[mi][r], off);
  if (ln == 0) {
    float b2 = cb2[0];
#pragma unroll
    for (int mi = 0; mi < 2; mi++)
#pragma unroll
      for (int r = 0; r < 4; r++) {
        int node = base + wave * 32 + mi * 16 + quad * 4 + r;
        if (node < N) wec[node] = sigf(part[mi][r] + b2);
      }
  }
}

// single-block exclusive scan of indeg -> rowptr (256 threads)
__device__ __forceinline__ void scan_body(
    int* wsum, const int* __restrict__ indeg, int* __restrict__ rowptr, int N) {
  int t = threadIdx.x;
  int lane = t & 63, wv = t >> 6;
  int runbase = 0;
  for (int c0 = 0; c0 < N; c0 += 1024) {
    int i = c0 + t * 4;
    int v0 = 0, v1 = 0, v2 = 0, v3 = 0;
    if (i + 0 < N) v0 = indeg[i + 0];
    if (i + 1 < N) v1 = indeg[i + 1];
    if (i + 2 < N) v2 = indeg[i + 2];
    if (i + 3 < N) v3 = indeg[i + 3];
    int tsum = v0 + v1 + v2 + v3;
    int x = tsum;
#pragma unroll
    for (int d = 1; d < 64; d <<= 1) { int y = __shfl_up(x, d); if (lane >= d) x += y; }
    if (lane == 63) wsum[wv] = x;
    __syncthreads();
    int wo = 0;
    for (int w = 0; w < wv; w++) wo += wsum[w];
    int tot = wsum[0] + wsum[1] + wsum[2] + wsum[3];
    int excl = runbase + wo + x - tsum;
    if (i + 0 < N) rowptr[i + 0] = excl;
    if (i + 1 < N) rowptr[i + 1] = excl + v0;
    if (i + 2 < N) rowptr[i + 2] = excl + v0 + v1;
    if (i + 3 < N) rowptr[i + 3] = excl + v0 + v1 + v2;
    runbase += tot;
    __syncthreads();
  }
  if (t == 0) rowptr[N] = runbase;
}

__global__ __launch_bounds__(256) void mega2_kernel(
    const float* __restrict__ emb, const unsigned short* __restrict__ PBc,
    const float* __restrict__ cb1, const float* __restrict__ cw2,
    const float* __restrict__ cb2, float* __restrict__ wec,
    const int* __restrict__ indeg, int* __restrict__ rowptr, int N, int GC) {
  __shared__ __align__(16) unsigned short astage[128 * 264];
  int b = blockIdx.x;
  if (b < GC) {
    conf_body(b, astage, emb, PBc, cb1, cw2, cb2, wec, N);
  } else {
    scan_body((int*)astage, indeg, rowptr, N);
  }
}

// ---------------------------------------------------------------------------
// K-scatterrank: CSR placement with NO atomics — rank was captured in pass 1.
// ---------------------------------------------------------------------------
__global__ void scatterrank_kernel(const int* __restrict__ ei,
                                   const int* __restrict__ rowptr,
                                   const int* __restrict__ erank,
                                   int* __restrict__ csr, int E, int N) {
  int idx = blockIdx.x * 256 + threadIdx.x;
  if (idx >= E + N) return;
  int src, dst;
  if (idx < E) { src = ei[idx]; dst = ei[E + idx]; } else { src = dst = idx - E; }
  csr[rowptr[dst] + erank[idx]] = src;
}

// ---------------------------------------------------------------------------
// K-gather: standalone, 16 lanes/node (head h = sub&3, parity par = sub>>2).
// Single pass (bounded logits -> no segment-max; softmax shift-invariant).
// ---------------------------------------------------------------------------
__global__ __launch_bounds__(256) void gather_kernel(
    const int* __restrict__ rowptr, const int* __restrict__ csr,
    const float* __restrict__ was, const float* __restrict__ wad,
    const float* __restrict__ wp12, const int* __restrict__ wlab,
    const int* __restrict__ outdeg, const float* __restrict__ gW,
    const float* __restrict__ gb, float* __restrict__ wgc,
    float* __restrict__ wag, int N) {
  __shared__ float sgW[400];
  int tid = threadIdx.x;
  for (int i = tid; i < 400; i += 256) sgW[i] = gW[i];
  __syncthreads();
  int vgid = blockIdx.x * 256 + tid;
  int node = vgid >> 4, sub = vgid & 15, h = sub & 3, par = sub >> 2;
  if (node >= N) return;
  int beg = rowptr[node], end = rowptr[node + 1];
  float ad = wad[(size_t)node * 4 + h];
  int mylab = wlab[node];
  float ssum = 0.f, cnt = 0.f;
  float z[10];
#pragma unroll
  for (int c = 0; c < 10; c++) z[c] = 0.f;
  for (int e = beg + par; e < end; e += 4) {
    int s = csr[e];
    float v = was[(size_t)s * 4 + h] + ad;
    float lr = v >= 0.f ? v : 0.2f * v;
    float ex = fexp2(LOG2E * lr);
    ssum += ex;
    const float4* pp = (const float4*)(wp12 + (size_t)s * 12);
    float4 p0 = pp[0], p1 = pp[1], p2 = pp[2];
    z[0] += ex * p0.x; z[1] += ex * p0.y; z[2] += ex * p0.z; z[3] += ex * p0.w;
    z[4] += ex * p1.x; z[5] += ex * p1.y; z[6] += ex * p1.z; z[7] += ex * p1.w;
    z[8] += ex * p2.x; z[9] += ex * p2.y;
    cnt += (wlab[s] == mylab) ? 1.f : 0.f;
  }
  // combine 4 edge parities (lane bits 2,3)
  ssum += __shfl_xor(ssum, 4); ssum += __shfl_xor(ssum, 8);
  cnt  += __shfl_xor(cnt, 4);  cnt  += __shfl_xor(cnt, 8);
#pragma unroll
  for (int c = 0; c < 10; c++) { z[c] += __shfl_xor(z[c], 4); z[c] += __shfl_xor(z[c], 8); }
  float inv = 1.f / (ssum + 1e-16f);
  float gpart[10];
#pragma unroll
  for (int c = 0; c < 10; c++) {
    float t = 0.f;
#pragma unroll
    for (int k = 0; k < 10; k++) t += z[k] * sgW[k * 40 + h * 10 + c];
    gpart[c] = t * inv;
  }
  // head mean reduce (lane bits 0,1)
#pragma unroll
  for (int c = 0; c < 10; c++) {
    gpart[c] += __shfl_xor(gpart[c], 1);
    gpart[c] += __shfl_xor(gpart[c], 2);
  }
  if (sub == 0) {
    float num = 0.f, np2 = 0.f, ng2 = 0.f;
    const float* pn = wp12 + (size_t)node * 12;
#pragma unroll
    for (int c = 0; c < 10; c++) {
      float g = gpart[c] * 0.25f + gb[c];
      float p = pn[c];
      num += p * g;
      np2 += p * p;
      ng2 += g * g;
    }
    float den = fmaxf(sqrtf(np2) * sqrtf(ng2), 1e-8f);
    wgc[node] = (num / den + 1.f) * 0.5f;
    float dgv = (float)outdeg[node];
    wag[node] = cnt / (dgv + 1e-8f);
  }
}

// ---------------------------------------------------------------------------
// K-lstm: fused 2-layer LSTM, fp8, 32 nodes/block, 512 threads (8 waves).
// Exact round-8 proven config: (512,2), no setprio, weights register-resident.
// Combine folded into the 32-thread tail.
// ---------------------------------------------------------------------------
#define HB2 4352  // 32*136

__global__ __launch_bounds__(512, 2) void lstm_kernel(
    const float* __restrict__ pred, const unsigned char* __restrict__ PB1,
    const unsigned char* __restrict__ PB2,
    const float* __restrict__ bih0, const float* __restrict__ bhh0,
    const float* __restrict__ bih1, const float* __restrict__ bhh1,
    const float* __restrict__ wmp, const float* __restrict__ wec,
    const float* __restrict__ wgc, const float* __restrict__ wag,
    float* __restrict__ out, int N) {
  __shared__ __align__(16) unsigned char hb[4 * HB2];  // h1: [0],[HB2]; h2: [2HB2],[3HB2]
  __shared__ __align__(16) unsigned char xbuf[32 * 40];
  __shared__ float varsum[32];
  int tid = threadIdx.x;
  int base = blockIdx.x * 32;
  for (int i = tid * 4; i < HB2; i += 2048) *(int*)&hb[3 * HB2 + i] = 0;  // h2[-1]=0
  for (int i = tid; i < 32 * 40; i += 512) {
    int nd = i / 40, o = i - nd * 40;
    float v = 0.f;
    if (o < 10 && base + nd < N) v = pred[(size_t)(base + nd) * NC + o];
    xbuf[i] = f2fp8(v);
  }
  if (tid < 32) varsum[tid] = 0.f;
  int wave = tid >> 6, lane = tid & 63, quad = lane >> 4, ln = lane & 15;
  float b0f[4], b1f[4];
#pragma unroll
  for (int g = 0; g < 4; g++) {
    int row = g * 128 + wave * 16 + ln;
    b0f[g] = bih0[row] + bhh0[row];
    b1f[g] = bih1[row] + bhh1[row];
  }
  long w1r[5][4], w2r[8][4];
#pragma unroll
  for (int ks = 0; ks < 5; ks++)
#pragma unroll
    for (int g = 0; g < 4; g++)
      w1r[ks][g] = *(const long*)(PB1 + (size_t)(((ks * 8 + wave) * 4 + g) * 64 + lane) * 8);
#pragma unroll
  for (int ks = 0; ks < 8; ks++)
#pragma unroll
    for (int g = 0; g < 4; g++)
      w2r[ks][g] = *(const long*)(PB2 + (size_t)(((ks * 8 + wave) * 4 + g) * 64 + lane) * 8);
  float c1[8], c2[8], s1[8], s2[8];
#pragma unroll
  for (int i = 0; i < 8; i++) { c1[i] = 0.f; c2[i] = 0.f; s1[i] = 0.f; s2[i] = 0.f; }
  const int hq = quad * 8;
  const int ucol = wave * 16 + ln;
  int arow[2], wrow[2];
#pragma unroll
  for (int mt = 0; mt < 2; mt++) {
    arow[mt] = (mt * 16 + ln) * 136 + hq;
    wrow[mt] = (mt * 16 + quad * 4) * 136 + ucol;
  }
  __syncthreads();  // xbuf ready
  long xa[2];
  xa[0] = *(const long*)&xbuf[ln * 40 + hq];
  xa[1] = *(const long*)&xbuf[(16 + ln) * 40 + hq];

  // ----- prime: phase1(t=0), h1 state = 0 -----
  {
    floatx4 acc[2][4];
#pragma unroll
    for (int mt = 0; mt < 2; mt++)
#pragma unroll
      for (int g = 0; g < 4; g++) acc[mt][g] = (floatx4){b0f[g], b0f[g], b0f[g], b0f[g]};
#pragma unroll
    for (int g = 0; g < 4; g++)
#pragma unroll
      for (int mt = 0; mt < 2; mt++) acc[mt][g] = mfma8(xa[mt], w1r[4][g], acc[mt][g]);
#pragma unroll
    for (int mt = 0; mt < 2; mt++)
#pragma unroll
      for (int r = 0; r < 4; r++) {
        int ci = mt * 4 + r;
        float ig = sig2(acc[mt][0][r]);
        float gg = tanh2(acc[mt][2][r]);
        float og = sig2(acc[mt][3][r]);
        float c = ig * gg;
        c1[ci] = c;
        hb[0 + wrow[mt] + r * 136] = f2fp8(og * tanh2(c));
      }
  }

#define LSTM_SEG(O1R, O1W, O2R, O2W, lastseg)                                    \
  {                                                                              \
    __syncthreads();                                                             \
    floatx4 acc[2][4];                                                           \
    _Pragma("unroll") for (int mt = 0; mt < 2; mt++)                             \
        _Pragma("unroll") for (int g = 0; g < 4; g++)                            \
            acc[mt][g] = (floatx4){b1f[g], b1f[g], b1f[g], b1f[g]};              \
    _Pragma("unroll") for (int ks = 0; ks < 8; ks++) {                           \
      long a_[2];                                                                \
      if (ks < 4) {                                                              \
        _Pragma("unroll") for (int mt = 0; mt < 2; mt++)                         \
            a_[mt] = *(const long*)&hb[(O1R) + arow[mt] + ks * 32];              \
      } else {                                                                   \
        _Pragma("unroll") for (int mt = 0; mt < 2; mt++)                         \
            a_[mt] = *(const long*)&hb[(O2R) + arow[mt] + (ks - 4) * 32];        \
      }                                                                          \
      _Pragma("unroll") for (int g = 0; g < 4; g++)                              \
          _Pragma("unroll") for (int mt = 0; mt < 2; mt++)                       \
              acc[mt][g] = mfma8(a_[mt], w2r[ks][g], acc[mt][g]);                \
    }                                                                            \
    _Pragma("unroll") for (int mt = 0; mt < 2; mt++)                             \
        _Pragma("unroll") for (int r = 0; r < 4; r++) {                          \
      int ci = mt * 4 + r;                                                       \
      float ig = sig2(acc[mt][0][r]);                                            \
      float fg = sig2(acc[mt][1][r]);                                            \
      float gg = tanh2(acc[mt][2][r]);                                           \
      float og = sig2(acc[mt][3][r]);                                            \
      float c = fg * c2[ci] + ig * gg;                                           \
      c2[ci] = c;                                                                \
      float h = og * tanh2(c);                                                   \
      s1[ci] += h;                                                               \
      s2[ci] += h * h;                                                           \
      hb[(O2W) + wrow[mt] + r * 136] = f2fp8(h);                                 \
    }                                                                            \
    if (!(lastseg)) {                                                            \
      _Pragma("unroll") for (int mt = 0; mt < 2; mt++)                           \
          _Pragma("unroll") for (int g = 0; g < 4; g++)                          \
              acc[mt][g] = (floatx4){b0f[g], b0f[g], b0f[g], b0f[g]};            \
      _Pragma("unroll") for (int ks = 0; ks < 5; ks++) {                         \
        long a_[2];                                                              \
        if (ks < 4) {                                                            \
          _Pragma("unroll") for (int mt = 0; mt < 2; mt++)                       \
              a_[mt] = *(const long*)&hb[(O1R) + arow[mt] + ks * 32];            \
        } else {                                                                 \
          a_[0] = xa[0]; a_[1] = xa[1];                                          \
        }                                                                        \
        _Pragma("unroll") for (int g = 0; g < 4; g++)                            \
            _Pragma("unroll") for (int mt = 0; mt < 2; mt++)                     \
                acc[mt][g] = mfma8(a_[mt], w1r[ks][g], acc[mt][g]);              \
      }                                                                          \
      _Pragma("unroll") for (int mt = 0; mt < 2; mt++)                           \
          _Pragma("unroll") for (int r = 0; r < 4; r++) {                        \
        int ci = mt * 4 + r;                                                     \
        float ig = sig2(acc[mt][0][r]);                                          \
        float fg = sig2(acc[mt][1][r]);                                          \
        float gg = tanh2(acc[mt][2][r]);                                         \
        float og = sig2(acc[mt][3][r]);                                          \
        float c = fg * c1[ci] + ig * gg;                                         \
        c1[ci] = c;                                                              \
        hb[(O1W) + wrow[mt] + r * 136] = f2fp8(og * tanh2(c));                   \
      }                                                                          \
    }                                                                            \
  }

  for (int tt = 0; tt < TSTEPS / 2; tt++) {
    LSTM_SEG(0, HB2, 3 * HB2, 2 * HB2, false);
    LSTM_SEG(HB2, 0, 2 * HB2, 3 * HB2, tt == TSTEPS / 2 - 1);
  }
#undef LSTM_SEG

  // variance (ddof=1) per (node,unit), summed over 128 units via LDS atomics
#pragma unroll
  for (int mt = 0; mt < 2; mt++)
#pragma unroll
    for (int r = 0; r < 4; r++) {
      int ci = mt * 4 + r;
      float m = s1[ci] * (1.f / 12.f);
      float var = (s2[ci] - 12.f * m * m) * (1.f / 11.f);
      atomicAdd(&varsum[mt * 16 + quad * 4 + r], var);
    }
  __syncthreads();
  // fused combine tail (only consumer of tc; wmp/wec/wgc/wag all ready)
  if (tid < 32 && base + tid < N) {
    int node = base + tid;
    float tc = 1.f / (1.f + varsum[tid] * (1.f / 128.f));
    float mp = wmp[node], ec = wec[node], gc = wgc[node];
    float comb = 0.4f * mp + 0.2f * ec + 0.2f * tc + 0.2f * gc;
    bool mask = (comb > 0.85f) && (wag[node] >= 0.6f);
    out[(size_t)1 * N + node] = comb;
    out[(size_t)2 * N + node] = mask ? 1.f : 0.f;
    out[(size_t)4 * N + node] = ec;
    out[(size_t)5 * N + node] = tc;
    out[(size_t)6 * N + node] = gc;
  }
}

// ---------------------------------------------------------------------------
extern "C" void kernel_launch(void* const* d_in, const int* in_sizes, int n_in,
                              void* d_out, int out_size, void* d_ws, size_t ws_size,
                              hipStream_t stream) {
  const float* emb  = (const float*)d_in[0];
  const float* pred = (const float*)d_in[1];
  const int*   ei   = (const int*)d_in[3];
  const float* cw1  = (const float*)d_in[4];
  const float* cb1  = (const float*)d_in[5];
  const float* cw2  = (const float*)d_in[6];
  const float* cb2  = (const float*)d_in[7];
  const float* wih0 = (const float*)d_in[8];
  const float* whh0 = (const float*)d_in[9];
  const float* bih0 = (const float*)d_in[10];
  const float* bhh0 = (const float*)d_in[11];
  const float* wih1 = (const float*)d_in[12];
  const float* whh1 = (const float*)d_in[13];
  const float* bih1 = (const float*)d_in[14];
  const float* bhh1 = (const float*)d_in[15];
  const float* gW   = (const float*)d_in[16];
  const float* gas  = (const float*)d_in[17];
  const float* gad  = (const float*)d_in[18];
  const float* gb   = (const float*)d_in[19];

  const int N = in_sizes[0] / HIDN;
  const int E = in_sizes[3] / 2;
  float* out = (float*)d_out;
  float* ws = (float*)d_ws;
  const size_t sN = (size_t)N;
  const size_t sE = (size_t)E;

  float* wp12   = ws;                         // 12N
  float* was    = ws + 12 * sN;               // 4N
  float* wad    = ws + 16 * sN;               // 4N
  int*   wlab   = (int*)(ws + 20 * sN);       // N
  float* wmp    = ws + 21 * sN;               // N
  float* wec    = ws + 22 * sN;               // N
  float* wgc    = ws + 24 * sN;               // N
  float* wag    = ws + 25 * sN;               // N
  int* indeg    = (int*)(ws + 26 * sN);       // N   <- memset region start
  int* outdeg   = (int*)(ws + 27 * sN);       // N   <- memset region end
  int* rowptr   = (int*)(ws + 28 * sN);       // N+1 (+pad)
  int* erank    = (int*)(ws + 29 * sN) + 64;  // E+N
  int* csr      = erank + sE + sN + 64;       // E+N
  float* pbase  = (float*)(csr + sE + sN + 64);
  unsigned char* PB1 = (unsigned char*)pbase;                  // 81920 B
  unsigned char* PB2 = (unsigned char*)(pbase + 20480);        // 131072 B
  unsigned short* PBc = (unsigned short*)(pbase + 53248);      // 32768 ushort

  hipMemsetAsync(indeg, 0, 2 * sN * sizeof(int), stream);

  // L1a: probs
  probs_kernel<<<(N + 255) / 256, 256, 0, stream>>>(
      pred, gW, gas, gad, out, wp12, was, wad, wlab, wmp, N);
  // L1b: pack
  pack_kernel<<<512, 256, 0, stream>>>(whh0, wih0, wih1, whh1, cw1, PB1, PB2, PBc);
  // L1c: rankhist (indeg atomic return = edge rank; stored to erank)
  int ne = E + N;
  rankhist_kernel<<<(ne + 255) / 256, 256, 0, stream>>>(ei, indeg, outdeg, erank, E, N);

  // L2: conf U mono-scan
  int GC = (N + 127) / 128;
  mega2_kernel<<<GC + 1, 256, 0, stream>>>(
      emb, PBc, cb1, cw2, cb2, wec, indeg, rowptr, N, GC);

  // L3: scatter via rank (no atomics)
  scatterrank_kernel<<<(ne + 255) / 256, 256, 0, stream>>>(ei, rowptr, erank, csr, E, N);

  // L4: gather (standalone, full occupancy)
  gather_kernel<<<(16 * N + 255) / 256, 256, 0, stream>>>(
      rowptr, csr, was, wad, wp12, wlab, outdeg, gW, gb, wgc, wag, N);

  // L5: lstm + fused combine tail
  lstm_kernel<<<(N + 31) / 32, 512, 0, stream>>>(
      pred, PB1, PB2, bih0, bhh0, bih1, bhh1, wmp, wec, wgc, wag, out, N);
}

// Round 9
// 1332.259 us; speedup vs baseline: 2.8777x; 1.0595x over previous
//
#include <hip/hip_runtime.h>
#include <hip/hip_bf16.h>

// ============================================================================
// PseudoLabelGenerator: round 15 — tail attack #2:
//   1. XCD-sharded rank counters: rankhist atomics go to plane blockIdx&7
//      (≈ local XCD's L2 under round-robin dispatch). Global rank recovered
//      via per-node shard prefixes in the scan (exact; mapping is perf-only).
//   2. wp16 record (64B): probs[10]+a_src[4]+label packed; gather = 4
//      lanes/node, each lane does ALL 4 heads from ONE record read ->
//      per-edge scattered fetch ~300B -> 128B.
//   3-launch parallel scan (scan1/2/3) extended to emit shbase + outdeg.
//   lstm (proven 726us config) and pack unchanged.
// ============================================================================

#define HIDN 256
#define NC 10
#define TSTEPS 12
#define NHEADS 4
#define LH 128

typedef __attribute__((ext_vector_type(8))) short short8;
typedef __attribute__((ext_vector_type(4))) float floatx4;

__device__ __forceinline__ unsigned short f2bf(float x) {
  unsigned u = __float_as_uint(x);
  u = u + 0x7FFFu + ((u >> 16) & 1u);   // round-to-nearest-even
  return (unsigned short)(u >> 16);
}
__device__ __forceinline__ unsigned char f2fp8(float x) {
  return (unsigned char)(__builtin_amdgcn_cvt_pk_fp8_f32(x, 0.f, 0, false) & 0xff);
}
__device__ __forceinline__ float fexp2(float x) { return __builtin_amdgcn_exp2f(x); }
__device__ __forceinline__ float frcpf(float x) { return __builtin_amdgcn_rcpf(x); }
#define LOG2E 1.44269504f
__device__ __forceinline__ float sigf(float x) {
  return frcpf(1.0f + fexp2(-LOG2E * x));
}
__device__ __forceinline__ float sig2(float x) {
  return frcpf(1.f + fexp2(-LOG2E * x));
}
__device__ __forceinline__ float tanh2(float x) {
  return 1.f - 2.f * frcpf(1.f + fexp2((2.f * LOG2E) * x));
}
__device__ __forceinline__ floatx4 mfma16(short8 a, short8 b, floatx4 c) {
  return __builtin_amdgcn_mfma_f32_16x16x32_bf16(a, b, c, 0, 0, 0);
}
__device__ __forceinline__ floatx4 mfma8(long a, long b, floatx4 c) {
  return __builtin_amdgcn_mfma_f32_16x16x32_fp8_fp8(a, b, c, 0, 0, 0);
}

// ---------------------------------------------------------------------------
// K-probs: softmax/argmax/entropy + wp16 record {p[10], as[4], lab, 0} + wad
// ---------------------------------------------------------------------------
__global__ __launch_bounds__(256) void probs_kernel(
    const float* __restrict__ pred, const float* __restrict__ gW,
    const float* __restrict__ gas, const float* __restrict__ gad,
    float* __restrict__ out, float* __restrict__ wp16,
    float* __restrict__ wad, float* __restrict__ wmp, int N) {
  __shared__ float sgW[400], sgas[40], sgad[40];
  int tid = threadIdx.x;
  for (int i = tid; i < 400; i += 256) sgW[i] = gW[i];
  if (tid < 40) { sgas[tid] = gas[tid]; sgad[tid] = gad[tid]; }
  __syncthreads();
  int node = blockIdx.x * 256 + tid;
  if (node >= N) return;
  const float* pr = pred + (size_t)node * NC;
  float p[NC];
#pragma unroll
  for (int c = 0; c < NC; c++) p[c] = pr[c];
  float pm = p[0]; int arg = 0;
#pragma unroll
  for (int c = 1; c < NC; c++) if (p[c] > pm) { pm = p[c]; arg = c; }
  float s = 0.f, prb[NC];
#pragma unroll
  for (int c = 0; c < NC; c++) { prb[c] = __expf(p[c] - pm); s += prb[c]; }
  float inv = 1.f / s;
  float ent = 0.f;
#pragma unroll
  for (int c = 0; c < NC; c++) {
    prb[c] *= inv;
    ent -= prb[c] * __logf(prb[c] + 1e-8f);
  }
  out[node] = (float)arg;
  out[(size_t)3 * N + node] = inv;
  out[(size_t)7 * N + node] = ent * (1.f / 2.302585093f);
  wmp[node] = inv;
  float xv[40];
#pragma unroll
  for (int hc = 0; hc < 40; hc++) {
    float t = 0.f;
#pragma unroll
    for (int k = 0; k < NC; k++) t += prb[k] * sgW[k * 40 + hc];
    xv[hc] = t;
  }
  float asv[4];
#pragma unroll
  for (int h = 0; h < NHEADS; h++) {
    float as = 0.f, ad = 0.f;
#pragma unroll
    for (int c = 0; c < NC; c++) { as += xv[h * 10 + c] * sgas[h * 10 + c]; ad += xv[h * 10 + c] * sgad[h * 10 + c]; }
    asv[h] = as;
    wad[(size_t)node * 4 + h] = ad;
  }
  float4* wp = (float4*)(wp16 + (size_t)node * 16);
  wp[0] = make_float4(prb[0], prb[1], prb[2], prb[3]);
  wp[1] = make_float4(prb[4], prb[5], prb[6], prb[7]);
  wp[2] = make_float4(prb[8], prb[9], asv[0], asv[1]);
  wp[3] = make_float4(asv[2], asv[3], __int_as_float(arg), 0.f);
}

// ---------------------------------------------------------------------------
// K-pack: weight packing (unchanged)
// ---------------------------------------------------------------------------
__global__ __launch_bounds__(256) void pack_kernel(
    const float* __restrict__ whh0, const float* __restrict__ wih0,
    const float* __restrict__ wih1, const float* __restrict__ whh1,
    const float* __restrict__ cw1,
    unsigned char* __restrict__ PB1, unsigned char* __restrict__ PB2,
    unsigned short* __restrict__ PBc) {
  int idx = blockIdx.x * 256 + threadIdx.x;
  if (idx < 81920) {  // PB1: 5ks*8w*4g*64*8 bytes
    int j = idx & 7, lane = (idx >> 3) & 63, rest = idx >> 9;
    int g = rest & 3, w = (rest >> 2) & 7, ks = rest >> 5;
    int k = ks * 32 + ((lane >> 4) << 3) + j;
    int u = w * 16 + (lane & 15), row = g * 128 + u;
    float val = 0.f;
    if (k < 128) val = whh0[row * 128 + k];
    else if (k < 138) val = wih0[row * 10 + (k - 128)];
    PB1[idx] = f2fp8(val);
  }
  if (idx < 131072) {  // PB2: 8ks*8w*4g*64*8 bytes
    int j = idx & 7, lane = (idx >> 3) & 63, rest = idx >> 9;
    int g = rest & 3, w = (rest >> 2) & 7, ks = rest >> 5;
    int k = ks * 32 + ((lane >> 4) << 3) + j;
    int u = w * 16 + (lane & 15), row = g * 128 + u;
    float val = (k < 128) ? wih1[row * 128 + k] : whh1[row * 128 + (k - 128)];
    PB2[idx] = f2fp8(val);
  }
  if (idx < 32768) {  // PBc: 8*8*64*8 bf16
    int j = idx & 7, lane = (idx >> 3) & 63, t2 = idx >> 9;
    int ti = t2 & 7, ks = t2 >> 3;
    int n = ti * 16 + (lane & 15);
    int k = ks * 32 + ((lane >> 4) << 3) + j;
    PBc[idx] = f2bf(cw1[n * 256 + k]);
  }
}

// ---------------------------------------------------------------------------
// K-rankhist: sharded degree counters; shard = blockIdx&7 (≈ XCD under
// round-robin dispatch -> atomics stay in local L2; correctness mapping-
// independent). indeg atomic's return = shard-local rank -> erank.
// ---------------------------------------------------------------------------
__global__ void rankhist_kernel(const int* __restrict__ ei, int* __restrict__ shin,
                                int* __restrict__ shout, int* __restrict__ erank,
                                int E, int N) {
  int idx = blockIdx.x * 256 + threadIdx.x;
  if (idx >= E + N) return;
  int sh = blockIdx.x & 7;
  int src, dst;
  if (idx < E) { src = ei[idx]; dst = ei[E + idx]; } else { src = dst = idx - E; }
  int r = atomicAdd(&shin[(size_t)sh * N + dst], 1);
  atomicAdd(&shout[(size_t)sh * N + src], 1);
  erank[idx] = r;
}

// ---------------------------------------------------------------------------
// K-conf: confidence net (standalone; unchanged body)
// ---------------------------------------------------------------------------
__global__ __launch_bounds__(256) void conf_kernel(
    const float* __restrict__ emb, const unsigned short* __restrict__ PBc,
    const float* __restrict__ cb1, const float* __restrict__ cw2,
    const float* __restrict__ cb2, float* __restrict__ wec, int N) {
  __shared__ __align__(16) unsigned short astage[128 * 264];
  int tid = threadIdx.x;
  int base = blockIdx.x * 128;
  for (int i = tid * 4; i < 128 * 256; i += 1024) {
    int row = i >> 8, col = i & 255;
    float4 v = make_float4(0.f, 0.f, 0.f, 0.f);
    if (base + row < N) v = *(const float4*)(emb + (size_t)(base + row) * 256 + col);
    unsigned short* d = &astage[row * 264 + col];
    d[0] = f2bf(v.x); d[1] = f2bf(v.y); d[2] = f2bf(v.z); d[3] = f2bf(v.w);
  }
  __syncthreads();
  int wave = tid >> 6, lane = tid & 63, quad = lane >> 4, ln = lane & 15;
  float b1f[8], w2f[8];
#pragma unroll
  for (int t = 0; t < 8; t++) { b1f[t] = cb1[t * 16 + ln]; w2f[t] = cw2[t * 16 + ln]; }
  floatx4 acc[2][8];
#pragma unroll
  for (int mi = 0; mi < 2; mi++)
#pragma unroll
    for (int t = 0; t < 8; t++) acc[mi][t] = (floatx4){b1f[t], b1f[t], b1f[t], b1f[t]};
#pragma unroll
  for (int ks = 0; ks < 8; ks++) {
    short8 a0 = *(const short8*)&astage[(wave * 32 + ln) * 264 + ks * 32 + quad * 8];
    short8 a1 = *(const short8*)&astage[(wave * 32 + 16 + ln) * 264 + ks * 32 + quad * 8];
    const unsigned short* bp = PBc + (((size_t)(ks * 8) * 64 + lane) << 3);
#pragma unroll
    for (int t = 0; t < 8; t++) {
      short8 b = *(const short8*)(bp + (size_t)t * 512);
      acc[0][t] = mfma16(a0, b, acc[0][t]);
      acc[1][t] = mfma16(a1, b, acc[1][t]);
    }
  }
  float part[2][4];
#pragma unroll
  for (int mi = 0; mi < 2; mi++)
#pragma unroll
    for (int r = 0; r < 4; r++) {
      float t = 0.f;
#pragma unroll
      for (int ti = 0; ti < 8; ti++) t += fmaxf(acc[mi][ti][r], 0.f) * w2f[ti];
      part[mi][r] = t;
    }
#pragma unroll
  for (int off = 8; off >= 1; off >>= 1)
#pragma unroll
    for (int mi = 0; mi < 2; mi++)
#pragma unroll
      for (int r = 0; r < 4; r++) part[mi][r] += __shfl_xor(part[mi][r], off);
  if (ln == 0) {
    float b2 = cb2[0];
#pragma unroll
    for (int mi = 0; mi < 2; mi++)
#pragma unroll
      for (int r = 0; r < 4; r++) {
        int node = base + wave * 32 + mi * 16 + quad * 4 + r;
        if (node < N) wec[node] = sigf(part[mi][r] + b2);
      }
  }
}

// ---------------------------------------------------------------------------
// K-scan1: sums 8 in-shards -> node total (+ shard prefixes into shbase),
// 8 out-shards -> outdeg. Block-local exclusive prefix -> rowptr.
// ---------------------------------------------------------------------------
__global__ __launch_bounds__(256) void scan1_kernel(
    const int* __restrict__ shin, const int* __restrict__ shout,
    int* __restrict__ shbase, int* __restrict__ outdeg,
    int* __restrict__ rowptr, int* __restrict__ partials, int N) {
  int t = threadIdx.x, b = blockIdx.x;
  int base = b * 1024 + t * 4;
  int tot[4];
#pragma unroll
  for (int j = 0; j < 4; j++) {
    int i = base + j;
    int run = 0;
    if (i < N) {
      int od = 0;
#pragma unroll
      for (int sh = 0; sh < 8; sh++) {
        int v = shin[(size_t)sh * N + i];
        shbase[(size_t)sh * N + i] = run;   // shard prefix (rowptr added in scan3)
        run += v;
        od += shout[(size_t)sh * N + i];
      }
      outdeg[i] = od;
    }
    tot[j] = run;
  }
  int tsum = tot[0] + tot[1] + tot[2] + tot[3];
  int lane = t & 63, wv = t >> 6;
  int x = tsum;
#pragma unroll
  for (int d = 1; d < 64; d <<= 1) { int y = __shfl_up(x, d); if (lane >= d) x += y; }
  __shared__ int wsum[4];
  if (lane == 63) wsum[wv] = x;
  __syncthreads();
  int wo = 0;
  for (int i = 0; i < wv; i++) wo += wsum[i];
  int excl = wo + x - tsum;
  if (base + 0 < N) rowptr[base + 0] = excl;
  if (base + 1 < N) rowptr[base + 1] = excl + tot[0];
  if (base + 2 < N) rowptr[base + 2] = excl + tot[0] + tot[1];
  if (base + 3 < N) rowptr[base + 3] = excl + tot[0] + tot[1] + tot[2];
  if (t == 255) partials[b] = wo + x;  // block total
}

__global__ void scan2_kernel(int* __restrict__ partials, int nb) {
  int t = threadIdx.x;
  int lane = t & 63, wv = t >> 6;
  int v = (t < nb) ? partials[t] : 0;
  int x = v;
#pragma unroll
  for (int d = 1; d < 64; d <<= 1) { int y = __shfl_up(x, d); if (lane >= d) x += y; }
  __shared__ int wsum[4];
  if (lane == 63) wsum[wv] = x;
  __syncthreads();
  int wo = 0;
  for (int i = 0; i < wv; i++) wo += wsum[i];
  if (t < nb) partials[t] = wo + x - v;  // exclusive
}

__global__ void scan3_kernel(int* __restrict__ rowptr, int* __restrict__ shbase,
                             const int* __restrict__ partials, int N, int total) {
  int i = blockIdx.x * 256 + threadIdx.x;
  if (i < N) {
    int r = rowptr[i] + partials[i >> 10];
    rowptr[i] = r;
#pragma unroll
    for (int sh = 0; sh < 8; sh++) shbase[(size_t)sh * N + i] += r;
  }
  if (i == 0) rowptr[N] = total;
}

// ---------------------------------------------------------------------------
// K-scatterrank: CSR placement, no atomics. pos = shbase[shard][dst] + rank.
// ---------------------------------------------------------------------------
__global__ void scatterrank_kernel(const int* __restrict__ ei,
                                   const int* __restrict__ shbase,
                                   const int* __restrict__ erank,
                                   int* __restrict__ csr, int E, int N) {
  int idx = blockIdx.x * 256 + threadIdx.x;
  if (idx >= E + N) return;
  int sh = (idx >> 8) & 7;  // == rankhist's blockIdx&7 for this idx
  int src, dst;
  if (idx < E) { src = ei[idx]; dst = ei[E + idx]; } else { src = dst = idx - E; }
  csr[shbase[(size_t)sh * N + dst] + erank[idx]] = src;
}

// ---------------------------------------------------------------------------
// K-gather: 4 lanes/node (edge parities); each lane computes ALL 4 heads
// from ONE 64B wp16 record read per edge. Rule #20: no runtime-indexed
// register arrays (head loops unrolled; par-select via branches).
// ---------------------------------------------------------------------------
__global__ __launch_bounds__(256) void gather_kernel(
    const int* __restrict__ rowptr, const int* __restrict__ csr,
    const float* __restrict__ wp16, const float* __restrict__ wad,
    const int* __restrict__ outdeg, const float* __restrict__ gW,
    const float* __restrict__ gb, float* __restrict__ wgc,
    float* __restrict__ wag, int N) {
  __shared__ float sgW[400];
  int tid = threadIdx.x;
  for (int i = tid; i < 400; i += 256) sgW[i] = gW[i];
  __syncthreads();
  int vgid = blockIdx.x * 256 + tid;
  int node = vgid >> 2, par = vgid & 3;
  if (node >= N) return;
  int beg = rowptr[node], end = rowptr[node + 1];
  float4 ad4 = *(const float4*)(wad + (size_t)node * 4);
  const float4* myrec = (const float4*)(wp16 + (size_t)node * 16);
  float4 m3 = myrec[3];
  int mylab = __float_as_int(m3.z);
  float ssum0 = 0.f, ssum1 = 0.f, ssum2 = 0.f, ssum3 = 0.f, cnt = 0.f;
  float z[4][10];
#pragma unroll
  for (int h = 0; h < 4; h++)
#pragma unroll
    for (int c = 0; c < 10; c++) z[h][c] = 0.f;
  for (int e = beg + par; e < end; e += 4) {
    int s = csr[e];
    const float4* rp = (const float4*)(wp16 + (size_t)s * 16);
    float4 r0 = rp[0], r1 = rp[1], r2 = rp[2], r3 = rp[3];
    float p[10] = {r0.x, r0.y, r0.z, r0.w, r1.x, r1.y, r1.z, r1.w, r2.x, r2.y};
    float as[4] = {r2.z, r2.w, r3.x, r3.y};
    float adh[4] = {ad4.x, ad4.y, ad4.z, ad4.w};
    cnt += (__float_as_int(r3.z) == mylab) ? 1.f : 0.f;
#pragma unroll
    for (int h = 0; h < 4; h++) {
      float v = as[h] + adh[h];
      float lr = v >= 0.f ? v : 0.2f * v;
      float ex = fexp2(LOG2E * lr);
      if (h == 0) ssum0 += ex; else if (h == 1) ssum1 += ex;
      else if (h == 2) ssum2 += ex; else ssum3 += ex;
#pragma unroll
      for (int c = 0; c < 10; c++) z[h][c] += ex * p[c];
    }
  }
  // parity combine (lane bits 0,1)
#pragma unroll
  for (int mask = 1; mask <= 2; mask <<= 1) {
    cnt += __shfl_xor(cnt, mask);
    ssum0 += __shfl_xor(ssum0, mask); ssum1 += __shfl_xor(ssum1, mask);
    ssum2 += __shfl_xor(ssum2, mask); ssum3 += __shfl_xor(ssum3, mask);
#pragma unroll
    for (int h = 0; h < 4; h++)
#pragma unroll
      for (int c = 0; c < 10; c++) z[h][c] += __shfl_xor(z[h][c], mask);
  }
  // this lane owns head h = par (compile-time copies per branch)
  float zp[10], sp;
  if (par == 0) { sp = ssum0;
#pragma unroll
    for (int c = 0; c < 10; c++) zp[c] = z[0][c];
  } else if (par == 1) { sp = ssum1;
#pragma unroll
    for (int c = 0; c < 10; c++) zp[c] = z[1][c];
  } else if (par == 2) { sp = ssum2;
#pragma unroll
    for (int c = 0; c < 10; c++) zp[c] = z[2][c];
  } else { sp = ssum3;
#pragma unroll
    for (int c = 0; c < 10; c++) zp[c] = z[3][c];
  }
  float inv = 1.f / (sp + 1e-16f);
  float gpart[10];
#pragma unroll
  for (int c = 0; c < 10; c++) {
    float t = 0.f;
#pragma unroll
    for (int k = 0; k < 10; k++) t += zp[k] * sgW[k * 40 + par * 10 + c];
    gpart[c] = t * inv;
  }
  // head-mean reduce
#pragma unroll
  for (int c = 0; c < 10; c++) {
    gpart[c] += __shfl_xor(gpart[c], 1);
    gpart[c] += __shfl_xor(gpart[c], 2);
  }
  if (par == 0) {
    float4 m0 = myrec[0], m1 = myrec[1], m2 = myrec[2];
    float pn[10] = {m0.x, m0.y, m0.z, m0.w, m1.x, m1.y, m1.z, m1.w, m2.x, m2.y};
    float num = 0.f, np2 = 0.f, ng2 = 0.f;
#pragma unroll
    for (int c = 0; c < 10; c++) {
      float g = gpart[c] * 0.25f + gb[c];
      float p = pn[c];
      num += p * g;
      np2 += p * p;
      ng2 += g * g;
    }
    float den = fmaxf(sqrtf(np2) * sqrtf(ng2), 1e-8f);
    wgc[node] = (num / den + 1.f) * 0.5f;
    float dgv = (float)outdeg[node];
    wag[node] = cnt / (dgv + 1e-8f);
  }
}

// ---------------------------------------------------------------------------
// K-lstm: unchanged (proven 726us config), combine folded into tail.
// ---------------------------------------------------------------------------
#define HB2 4352  // 32*136

__global__ __launch_bounds__(512, 2) void lstm_kernel(
    const float* __restrict__ pred, const unsigned char* __restrict__ PB1,
    const unsigned char* __restrict__ PB2,
    const float* __restrict__ bih0, const float* __restrict__ bhh0,
    const float* __restrict__ bih1, const float* __restrict__ bhh1,
    const float* __restrict__ wmp, const float* __restrict__ wec,
    const float* __restrict__ wgc, const float* __restrict__ wag,
    float* __restrict__ out, int N) {
  __shared__ __align__(16) unsigned char hb[4 * HB2];
  __shared__ __align__(16) unsigned char xbuf[32 * 40];
  __shared__ float varsum[32];
  int tid = threadIdx.x;
  int base = blockIdx.x * 32;
  for (int i = tid * 4; i < HB2; i += 2048) *(int*)&hb[3 * HB2 + i] = 0;
  for (int i = tid; i < 32 * 40; i += 512) {
    int nd = i / 40, o = i - nd * 40;
    float v = 0.f;
    if (o < 10 && base + nd < N) v = pred[(size_t)(base + nd) * NC + o];
    xbuf[i] = f2fp8(v);
  }
  if (tid < 32) varsum[tid] = 0.f;
  int wave = tid >> 6, lane = tid & 63, quad = lane >> 4, ln = lane & 15;
  float b0f[4], b1f[4];
#pragma unroll
  for (int g = 0; g < 4; g++) {
    int row = g * 128 + wave * 16 + ln;
    b0f[g] = bih0[row] + bhh0[row];
    b1f[g] = bih1[row] + bhh1[row];
  }
  long w1r[5][4], w2r[8][4];
#pragma unroll
  for (int ks = 0; ks < 5; ks++)
#pragma unroll
    for (int g = 0; g < 4; g++)
      w1r[ks][g] = *(const long*)(PB1 + (size_t)(((ks * 8 + wave) * 4 + g) * 64 + lane) * 8);
#pragma unroll
  for (int ks = 0; ks < 8; ks++)
#pragma unroll
    for (int g = 0; g < 4; g++)
      w2r[ks][g] = *(const long*)(PB2 + (size_t)(((ks * 8 + wave) * 4 + g) * 64 + lane) * 8);
  float c1[8], c2[8], s1[8], s2[8];
#pragma unroll
  for (int i = 0; i < 8; i++) { c1[i] = 0.f; c2[i] = 0.f; s1[i] = 0.f; s2[i] = 0.f; }
  const int hq = quad * 8;
  const int ucol = wave * 16 + ln;
  int arow[2], wrow[2];
#pragma unroll
  for (int mt = 0; mt < 2; mt++) {
    arow[mt] = (mt * 16 + ln) * 136 + hq;
    wrow[mt] = (mt * 16 + quad * 4) * 136 + ucol;
  }
  __syncthreads();  // xbuf ready
  long xa[2];
  xa[0] = *(const long*)&xbuf[ln * 40 + hq];
  xa[1] = *(const long*)&xbuf[(16 + ln) * 40 + hq];

  // ----- prime: phase1(t=0), h1 state = 0 -----
  {
    floatx4 acc[2][4];
#pragma unroll
    for (int mt = 0; mt < 2; mt++)
#pragma unroll
      for (int g = 0; g < 4; g++) acc[mt][g] = (floatx4){b0f[g], b0f[g], b0f[g], b0f[g]};
#pragma unroll
    for (int g = 0; g < 4; g++)
#pragma unroll
      for (int mt = 0; mt < 2; mt++) acc[mt][g] = mfma8(xa[mt], w1r[4][g], acc[mt][g]);
#pragma unroll
    for (int mt = 0; mt < 2; mt++)
#pragma unroll
      for (int r = 0; r < 4; r++) {
        int ci = mt * 4 + r;
        float ig = sig2(acc[mt][0][r]);
        float gg = tanh2(acc[mt][2][r]);
        float og = sig2(acc[mt][3][r]);
        float c = ig * gg;
        c1[ci] = c;
        hb[0 + wrow[mt] + r * 136] = f2fp8(og * tanh2(c));
      }
  }

#define LSTM_SEG(O1R, O1W, O2R, O2W, lastseg)                                    \
  {                                                                              \
    __syncthreads();                                                             \
    floatx4 acc[2][4];                                                           \
    _Pragma("unroll") for (int mt = 0; mt < 2; mt++)                             \
        _Pragma("unroll") for (int g = 0; g < 4; g++)                            \
            acc[mt][g] = (floatx4){b1f[g], b1f[g], b1f[g], b1f[g]};              \
    _Pragma("unroll") for (int ks = 0; ks < 8; ks++) {                           \
      long a_[2];                                                                \
      if (ks < 4) {                                                              \
        _Pragma("unroll") for (int mt = 0; mt < 2; mt++)                         \
            a_[mt] = *(const long*)&hb[(O1R) + arow[mt] + ks * 32];              \
      } else {                                                                   \
        _Pragma("unroll") for (int mt = 0; mt < 2; mt++)                         \
            a_[mt] = *(const long*)&hb[(O2R) + arow[mt] + (ks - 4) * 32];        \
      }                                                                          \
      _Pragma("unroll") for (int g = 0; g < 4; g++)                              \
          _Pragma("unroll") for (int mt = 0; mt < 2; mt++)                       \
              acc[mt][g] = mfma8(a_[mt], w2r[ks][g], acc[mt][g]);                \
    }                                                                            \
    _Pragma("unroll") for (int mt = 0; mt < 2; mt++)                             \
        _Pragma("unroll") for (int r = 0; r < 4; r++) {                          \
      int ci = mt * 4 + r;                                                       \
      float ig = sig2(acc[mt][0][r]);                                            \
      float fg = sig2(acc[mt][1][r]);                                            \
      float gg = tanh2(acc[mt][2][r]);                                           \
      float og = sig2(acc[mt][3][r]);                                            \
      float c = fg * c2[ci] + ig * gg;                                           \
      c2[ci] = c;                                                                \
      float h = og * tanh2(c);                                                   \
      s1[ci] += h;                                                               \
      s2[ci] += h * h;                                                           \
      hb[(O2W) + wrow[mt] + r * 136] = f2fp8(h);                                 \
    }                                                                            \
    if (!(lastseg)) {                                                            \
      _Pragma("unroll") for (int mt = 0; mt < 2; mt++)                           \
          _Pragma("unroll") for (int g = 0; g < 4; g++)                          \
              acc[mt][g] = (floatx4){b0f[g], b0f[g], b0f[g], b0f[g]};            \
      _Pragma("unroll") for (int ks = 0; ks < 5; ks++) {                         \
        long a_[2];                                                              \
        if (ks < 4) {                                                            \
          _Pragma("unroll") for (int mt = 0; mt < 2; mt++)                       \
              a_[mt] = *(const long*)&hb[(O1R) + arow[mt] + ks * 32];            \
        } else {                                                                 \
          a_[0] = xa[0]; a_[1] = xa[1];                                          \
        }                                                                        \
        _Pragma("unroll") for (int g = 0; g < 4; g++)                            \
            _Pragma("unroll") for (int mt = 0; mt < 2; mt++)                     \
                acc[mt][g] = mfma8(a_[mt], w1r[ks][g], acc[mt][g]);              \
      }                                                                          \
      _Pragma("unroll") for (int mt = 0; mt < 2; mt++)                           \
          _Pragma("unroll") for (int r = 0; r < 4; r++) {                        \
        int ci = mt * 4 + r;                                                     \
        float ig = sig2(acc[mt][0][r]);                                          \
        float fg = sig2(acc[mt][1][r]);                                          \
        float gg = tanh2(acc[mt][2][r]);                                         \
        float og = sig2(acc[mt][3][r]);                                          \
        float c = fg * c1[ci] + ig * gg;                                         \
        c1[ci] = c;                                                              \
        hb[(O1W) + wrow[mt] + r * 136] = f2fp8(og * tanh2(c));                   \
      }                                                                          \
    }                                                                            \
  }

  for (int tt = 0; tt < TSTEPS / 2; tt++) {
    LSTM_SEG(0, HB2, 3 * HB2, 2 * HB2, false);
    LSTM_SEG(HB2, 0, 2 * HB2, 3 * HB2, tt == TSTEPS / 2 - 1);
  }
#undef LSTM_SEG

#pragma unroll
  for (int mt = 0; mt < 2; mt++)
#pragma unroll
    for (int r = 0; r < 4; r++) {
      int ci = mt * 4 + r;
      float m = s1[ci] * (1.f / 12.f);
      float var = (s2[ci] - 12.f * m * m) * (1.f / 11.f);
      atomicAdd(&varsum[mt * 16 + quad * 4 + r], var);
    }
  __syncthreads();
  if (tid < 32 && base + tid < N) {
    int node = base + tid;
    float tc = 1.f / (1.f + varsum[tid] * (1.f / 128.f));
    float mp = wmp[node], ec = wec[node], gc = wgc[node];
    float comb = 0.4f * mp + 0.2f * ec + 0.2f * tc + 0.2f * gc;
    bool mask = (comb > 0.85f) && (wag[node] >= 0.6f);
    out[(size_t)1 * N + node] = comb;
    out[(size_t)2 * N + node] = mask ? 1.f : 0.f;
    out[(size_t)4 * N + node] = ec;
    out[(size_t)5 * N + node] = tc;
    out[(size_t)6 * N + node] = gc;
  }
}

// ---------------------------------------------------------------------------
extern "C" void kernel_launch(void* const* d_in, const int* in_sizes, int n_in,
                              void* d_out, int out_size, void* d_ws, size_t ws_size,
                              hipStream_t stream) {
  const float* emb  = (const float*)d_in[0];
  const float* pred = (const float*)d_in[1];
  const int*   ei   = (const int*)d_in[3];
  const float* cw1  = (const float*)d_in[4];
  const float* cb1  = (const float*)d_in[5];
  const float* cw2  = (const float*)d_in[6];
  const float* cb2  = (const float*)d_in[7];
  const float* wih0 = (const float*)d_in[8];
  const float* whh0 = (const float*)d_in[9];
  const float* bih0 = (const float*)d_in[10];
  const float* bhh0 = (const float*)d_in[11];
  const float* wih1 = (const float*)d_in[12];
  const float* whh1 = (const float*)d_in[13];
  const float* bih1 = (const float*)d_in[14];
  const float* bhh1 = (const float*)d_in[15];
  const float* gW   = (const float*)d_in[16];
  const float* gas  = (const float*)d_in[17];
  const float* gad  = (const float*)d_in[18];
  const float* gb   = (const float*)d_in[19];

  const int N = in_sizes[0] / HIDN;
  const int E = in_sizes[3] / 2;
  float* out = (float*)d_out;
  float* ws = (float*)d_ws;
  const size_t sN = (size_t)N;
  const size_t sE = (size_t)E;

  float* wp16   = ws;                          // 16N (64B records)
  float* wad    = ws + 16 * sN;                // 4N
  float* wmp    = ws + 20 * sN;                // N
  float* wec    = ws + 21 * sN;                // N
  float* wgc    = ws + 22 * sN;                // N
  float* wag    = ws + 23 * sN;                // N
  int* outdeg   = (int*)(ws + 24 * sN);        // N
  int* rowptr   = (int*)(ws + 25 * sN);        // N+1 (+pad 64)
  int* shin     = (int*)(ws + 26 * sN) + 64;   // 8N  <- memset start (16N ints)
  int* shout    = shin + 8 * sN;               // 8N  <- memset end
  int* shbase   = shout + 8 * sN;              // 8N
  int* partials = shbase + 8 * sN + 64;        // 256
  int* erank    = partials + 256 + 64;         // E+N
  int* csr      = erank + sE + sN + 64;        // E+N
  float* pbase  = (float*)(csr + sE + sN + 64);
  unsigned char* PB1 = (unsigned char*)pbase;                  // 81920 B
  unsigned char* PB2 = (unsigned char*)(pbase + 20480);        // 131072 B
  unsigned short* PBc = (unsigned short*)(pbase + 53248);      // 32768 ushort

  hipMemsetAsync(shin, 0, 16 * sN * sizeof(int), stream);

  probs_kernel<<<(N + 255) / 256, 256, 0, stream>>>(
      pred, gW, gas, gad, out, wp16, wad, wmp, N);
  pack_kernel<<<512, 256, 0, stream>>>(whh0, wih0, wih1, whh1, cw1, PB1, PB2, PBc);
  int ne = E + N;
  rankhist_kernel<<<(ne + 255) / 256, 256, 0, stream>>>(ei, shin, shout, erank, E, N);

  conf_kernel<<<(N + 127) / 128, 256, 0, stream>>>(emb, PBc, cb1, cw2, cb2, wec, N);

  int nb = (N + 1023) / 1024;
  scan1_kernel<<<nb, 256, 0, stream>>>(shin, shout, shbase, outdeg, rowptr, partials, N);
  scan2_kernel<<<1, 256, 0, stream>>>(partials, nb);
  scan3_kernel<<<(N + 255) / 256, 256, 0, stream>>>(rowptr, shbase, partials, N, ne);

  scatterrank_kernel<<<(ne + 255) / 256, 256, 0, stream>>>(ei, shbase, erank, csr, E, N);

  gather_kernel<<<(4 * N + 255) / 256, 256, 0, stream>>>(
      rowptr, csr, wp16, wad, outdeg, gW, gb, wgc, wag, N);

  lstm_kernel<<<(N + 31) / 32, 512, 0, stream>>>(
      pred, PB1, PB2, bih0, bhh0, bih1, bhh1, wmp, wec, wgc, wag, out, N);
}